// Round 7
// baseline (283.821 us; speedup 1.0000x reference)
//
#include <hip/hip_runtime.h>
#include <hip/hip_bf16.h>

#define NH 8
#define SQ 2048
#define HD 64
#define NTOT (NH * SQ * HD)   // 1048576

typedef unsigned short u16;
typedef unsigned int u32;
typedef __attribute__((ext_vector_type(8))) unsigned short us8;
typedef __attribute__((ext_vector_type(4))) unsigned short us4v;
typedef __attribute__((ext_vector_type(8))) _Float16 h8;   // MFMA f16 A/B fragment
typedef __attribute__((ext_vector_type(4))) float f4;      // MFMA C/D fragment
typedef __attribute__((ext_vector_type(4))) u32 u4;

#define MFMA_F16 __builtin_amdgcn_mfma_f32_16x16x32_f16

__device__ __forceinline__ u16 f2h(float f) {
    union { _Float16 h; u16 u; } c; c.h = (_Float16)f; return c.u;
}
__device__ __forceinline__ float h2f(u16 u) {
    union { _Float16 h; u16 u; } c; c.u = u; return (float)c.h;
}
__device__ __forceinline__ h8 neg_h8(h8 a) {
    union { h8 h; u4 u; } c; c.h = a;
    c.u ^= 0x80008000u;
    return c.h;
}
// 8 contiguous f32 -> f16x8 fragment (two float4 loads, hw cvt)
__device__ __forceinline__ h8 pack8h(const float* p) {
    float4 a = ((const float4*)p)[0];
    float4 b = ((const float4*)p)[1];
    h8 r;
    r[0] = (_Float16)a.x; r[1] = (_Float16)a.y; r[2] = (_Float16)a.z; r[3] = (_Float16)a.w;
    r[4] = (_Float16)b.x; r[5] = (_Float16)b.y; r[6] = (_Float16)b.z; r[7] = (_Float16)b.w;
    return r;
}

// T2 swizzle: pitch 64 u16 (128B rows), 16B-chunk index XOR'd with row&7.
__device__ __forceinline__ int swz8(int row, int chunk) {   // u16 offset of 8-u16 chunk
    return row * 64 + ((chunk ^ (row & 7)) << 3);
}

struct Afrag { h8 r0, r1, i0, i1, ni0, ni1; };

// ---------------------------------------------------------------------------
// Prep kernels (unchanged from R6).
// ---------------------------------------------------------------------------
__global__ __launch_bounds__(128) void prep1_kernel(
    const float* __restrict__ qwr, const float* __restrict__ qwi,
    const float* __restrict__ kwr, const float* __restrict__ kwi,
    const float* __restrict__ vwr, const float* __restrict__ vwi,
    const float* __restrict__ gwr, const float* __restrict__ gwi,
    u16* __restrict__ pk)
{
    const int b = blockIdx.x;
    const float* W; int nt;
    if (b < 8)       { W = qwr; nt = b; }
    else if (b < 16) { W = qwi; nt = b - 8; }
    else if (b < 20) { W = kwr; nt = b - 16; }
    else if (b < 24) { W = kwi; nt = b - 20; }
    else if (b < 28) { W = vwr; nt = b - 24; }
    else if (b < 32) { W = vwi; nt = b - 28; }
    else if (b < 36) { W = gwr; nt = b - 32; }
    else             { W = gwi; nt = b - 36; }
    const int t = threadIdx.x, hf = t >> 6, l = t & 63;
    const int quad = l >> 4, m16 = l & 15;
    h8 v = pack8h(W + (nt * 16 + m16) * 64 + hf * 32 + quad * 8);
    *(h8*)(pk + b * 1024 + hf * 512 + l * 8) = v;
}

__global__ __launch_bounds__(128) void prep2_kernel(
    const float* __restrict__ owr, const float* __restrict__ owi,
    u16* __restrict__ pk)
{
    const int b = blockIdx.x;
    const float* W = (b < 4) ? owr : owi;
    const int nt = b & 3;
    const int t = threadIdx.x, hf = t >> 6, l = t & 63;
    const int quad = l >> 4, m16 = l & 15;
    h8 v = pack8h(W + (nt * 16 + m16) * 64 + hf * 32 + quad * 8);
    *(h8*)(pk + b * 1024 + hf * 512 + l * 8) = v;
}

// ---------------------------------------------------------------------------
// Kernel 1: MFMA complex projections (unchanged from R6).
// ---------------------------------------------------------------------------
__global__ __launch_bounds__(256) void proj_kernel(
    const float* __restrict__ q_r, const float* __restrict__ q_i,
    const float* __restrict__ k_r, const float* __restrict__ k_i,
    const float* __restrict__ v_r, const float* __restrict__ v_i,
    const float* __restrict__ pe_q_r, const float* __restrict__ pe_q_i,
    const float* __restrict__ pe_k_r, const float* __restrict__ pe_k_i,
    const u16* __restrict__ pk,
    const float* __restrict__ qbr, const float* __restrict__ qbi,
    const float* __restrict__ kbr, const float* __restrict__ kbi,
    const float* __restrict__ vbr, const float* __restrict__ vbi,
    const float* __restrict__ gbr, const float* __restrict__ gbi,
    u16* __restrict__ q1r, u16* __restrict__ q1i,
    u16* __restrict__ q2r, u16* __restrict__ q2i,
    u16* __restrict__ kpr, u16* __restrict__ kpi,
    u16* __restrict__ vtr, u16* __restrict__ vti,
    float* __restrict__ out_gr, float* __restrict__ out_gi)
{
    __shared__ __align__(16) u16 Sqr[16 * 64], Sqi[16 * 64];
    __shared__ __align__(16) u16 Skr[16 * 64], Ski[16 * 64];
    __shared__ __align__(16) u16 Svr[16 * 64], Svi[16 * 64];

    const int t = threadIdx.x;
    const int wv = t >> 6, l = t & 63;
    const int quad = l >> 4, m16 = l & 15;
    const int rowbase = blockIdx.x * 16;
    const int h = rowbase >> 11;
    const int l8 = l * 8;

    // ---- stage 6 input tiles: coalesced float4 -> f16 -> swz8 LDS ----
    {
        const int r = t >> 4, c4 = (t & 15) * 4;
        const int off = swz8(r, c4 >> 3) + (c4 & 7);
        const size_t gi = (size_t)(rowbase + r) * 64 + c4;
        auto stage = [&](const float* src, u16* dst) {
            float4 v = *(const float4*)(src + gi);
            us4v p;
            p[0] = f2h(v.x); p[1] = f2h(v.y); p[2] = f2h(v.z); p[3] = f2h(v.w);
            *(us4v*)&dst[off] = p;
        };
        stage(q_r, Sqr); stage(q_i, Sqi);
        stage(k_r, Skr); stage(k_i, Ski);
        stage(v_r, Svr); stage(v_i, Svi);
    }
    __syncthreads();

    auto loadA = [&](const u16* Sr, const u16* Si) {
        Afrag a;
        a.r0 = *(const h8*)&Sr[swz8(m16, quad)];
        a.r1 = *(const h8*)&Sr[swz8(m16, quad + 4)];
        a.i0 = *(const h8*)&Si[swz8(m16, quad)];
        a.i1 = *(const h8*)&Si[swz8(m16, quad + 4)];
        a.ni0 = neg_h8(a.i0);
        a.ni1 = neg_h8(a.i1);
        return a;
    };

    auto ctile = [&](const Afrag& A, int planeR, int planeI, f4& Cr, f4& Ci) {
        const u16* pR = pk + planeR * 1024;
        const u16* pI = pk + planeI * 1024;
        h8 Br0 = *(const h8*)(pR + l8);
        h8 Br1 = *(const h8*)(pR + 512 + l8);
        h8 Bi0 = *(const h8*)(pI + l8);
        h8 Bi1 = *(const h8*)(pI + 512 + l8);
        Cr = (f4)0.f; Ci = (f4)0.f;
        Cr = MFMA_F16(A.r0,  Br0, Cr, 0, 0, 0);
        Cr = MFMA_F16(A.r1,  Br1, Cr, 0, 0, 0);
        Cr = MFMA_F16(A.ni0, Bi0, Cr, 0, 0, 0);
        Cr = MFMA_F16(A.ni1, Bi1, Cr, 0, 0, 0);
        Ci = MFMA_F16(A.r0,  Bi0, Ci, 0, 0, 0);
        Ci = MFMA_F16(A.r1,  Bi1, Ci, 0, 0, 0);
        Ci = MFMA_F16(A.i0,  Br0, Ci, 0, 0, 0);
        Ci = MFMA_F16(A.i1,  Br1, Ci, 0, 0, 0);
    };

    auto qtile = [&](const Afrag& A, int nt) {
        f4 Cr, Ci;
        ctile(A, nt, 8 + nt, Cr, Ci);
        int c = nt * 16 + m16;
        float br = qbr[c], bi = qbi[c];
        int dd = c >> 1, pc = c & 63;
        u16* dR = (c & 1) ? q2r : q1r;
        u16* dI = (c & 1) ? q2i : q1i;
        #pragma unroll
        for (int r = 0; r < 4; ++r) {
            int g = rowbase + quad * 4 + r;
            dR[g * 64 + dd] = f2h(Cr[r] + br + pe_q_r[g * 64 + pc]);
            dI[g * 64 + dd] = f2h(Ci[r] + bi + pe_q_i[g * 64 + pc]);
        }
    };
    auto ktile = [&](const Afrag& A, int nt) {
        f4 Cr, Ci;
        ctile(A, 16 + nt, 20 + nt, Cr, Ci);
        int c = nt * 16 + m16;
        float br = kbr[c], bi = kbi[c];
        #pragma unroll
        for (int r = 0; r < 4; ++r) {
            int g = rowbase + quad * 4 + r;
            kpr[g * 64 + c] = f2h(Cr[r] + br + pe_k_r[g * 64 + c]);
            kpi[g * 64 + c] = f2h(Ci[r] + bi + pe_k_i[g * 64 + c]);
        }
    };
    auto vtile = [&](const Afrag& A, int nt) {
        f4 Cr, Ci;
        ctile(A, 24 + nt, 28 + nt, Cr, Ci);
        int c = nt * 16 + m16;
        float br = vbr[c], bi = vbi[c];
        int s0 = (rowbase & 2047) + quad * 4;
        size_t tix = (size_t)(h * 64 + c) * 2048 + s0;
        us4v pr, pi;
        #pragma unroll
        for (int r = 0; r < 4; ++r) {
            pr[r] = f2h(Cr[r] + br);
            pi[r] = f2h(Ci[r] + bi);
        }
        *(us4v*)&vtr[tix] = pr;
        *(us4v*)&vti[tix] = pi;
    };
    auto gtile = [&](const Afrag& A, int nt) {
        f4 Cr, Ci;
        ctile(A, 32 + nt, 36 + nt, Cr, Ci);
        int c = nt * 16 + m16;
        float br = gbr[c], bi = gbi[c];
        #pragma unroll
        for (int r = 0; r < 4; ++r) {
            int g = rowbase + quad * 4 + r;
            out_gr[g * 64 + c] = Cr[r] + br;
            out_gi[g * 64 + c] = Ci[r] + bi;
        }
    };

    if (wv == 0) {
        Afrag Aq = loadA(Sqr, Sqi);
        qtile(Aq, 0); qtile(Aq, 1); qtile(Aq, 2); qtile(Aq, 3); qtile(Aq, 4);
    } else if (wv == 1) {
        Afrag Aq = loadA(Sqr, Sqi);
        qtile(Aq, 5); qtile(Aq, 6); qtile(Aq, 7);
        gtile(Aq, 0); gtile(Aq, 1);
    } else if (wv == 2) {
        Afrag Ak = loadA(Skr, Ski);
        ktile(Ak, 0); ktile(Ak, 1); ktile(Ak, 2); ktile(Ak, 3);
        Afrag Aq = loadA(Sqr, Sqi);
        gtile(Aq, 2);
    } else {
        Afrag Av = loadA(Svr, Svi);
        vtile(Av, 0); vtile(Av, 1); vtile(Av, 2); vtile(Av, 3);
        Afrag Aq = loadA(Sqr, Sqi);
        gtile(Aq, 3);
    }
}

// ---------------------------------------------------------------------------
// Kernel 2: MFMA flash attention.
//   Round-15: in-block split-K. Waves 0-3 (group A) process even k-tiles,
//   waves 4-7 (group B) odd k-tiles; each wave covers 32 q-rows (2 row-
//   tiles) so each group spans all 128 row-instances. Only 4 waves read
//   each staged tile -> DS-read traffic per tile HALVES (272->136 b128)
//   while keeping 2 waves/SIMD TLP. 3-slot rotating K/V buffers (96KB) +
//   256-row Pb (32KB) = 128KB LDS. 2 barriers per super-iter (= 1 per
//   tile, same rate as R5). Cross-group (m,L,O) merge via LDS at the end.
// ---------------------------------------------------------------------------
__global__ __launch_bounds__(512, 2) void attn_kernel(
    const u16* __restrict__ q1r, const u16* __restrict__ q1i,
    const u16* __restrict__ q2r, const u16* __restrict__ q2i,
    const u16* __restrict__ kpr, const u16* __restrict__ kpi,
    const u16* __restrict__ vtr, const u16* __restrict__ vti,
    u16* __restrict__ o1r, u16* __restrict__ o1i,
    u16* __restrict__ o2r, u16* __restrict__ o2i)
{
    // [slot][arr: Kr,Ki,Vr,Vi][64x64 u16]  (96KB) + Pb 256x64 (32KB) = 128KB
    __shared__ __align__(16) u16 TILE[3][4][4096];
    __shared__ __align__(16) u16 Pb[256 * 64];

    const int t  = threadIdx.x;      // 0..511
    const int qt = blockIdx.x;
    const int h  = blockIdx.z;

    const int wq   = t >> 6;         // wave 0..7
    const int grp  = wq >> 2;        // split-K group: 0=even tiles, 1=odd
    const int br   = (wq >> 1) & 1;  // branch
    const int rh   = wq & 1;         // 32-row half of the 64-row q tile
    const int l    = t & 63;
    const int quad = l >> 4;
    const int m    = l & 15;

    const u16* Qsr = br ? q2r : q1r;
    const u16* Qsi = br ? q2i : q1i;
    const int hbase = h * SQ * 64;
    const int qbase = hbase + qt * 64 * 64;
    const int vbase = h * 64 * SQ;

    // ---- Q fragments: 2 row-tiles (rows rh*32 + rs*16 + m) ----
    h8 Qr0[2], Qr1[2], Qi0[2], Qi1[2];
    #pragma unroll
    for (int rs = 0; rs < 2; ++rs) {
        const u16* qrr = Qsr + qbase + (rh * 32 + rs * 16 + m) * 64;
        const u16* qri = Qsi + qbase + (rh * 32 + rs * 16 + m) * 64;
        Qr0[rs] = *(const h8*)(qrr + quad * 8);
        Qr1[rs] = *(const h8*)(qrr + 32 + quad * 8);
        Qi0[rs] = *(const h8*)(qri + quad * 8);
        Qi1[rs] = *(const h8*)(qri + 32 + quad * 8);
    }

    // ---- staging: 512 threads cover one 64x64 u16 tile per array ----
    const int sr0 = t >> 3;           // row 0..63
    const int sc  = t & 7;            // 8-u16 chunk
    us8 rKa, rCa, rVa, rWa;           // pipeline A regs (even-slot commits)
    us8 rKb, rCb, rVb, rWb;           // pipeline B regs

    auto issueT = [&](int kt, us8& K, us8& C, us8& V, us8& W) {
        const int kb = hbase + kt * 4096;
        const int vb = vbase + kt * 64;
        const int sc8 = sc * 8;
        K = *(const us8*)(kpr + kb + sr0 * 64 + sc8);
        C = *(const us8*)(kpi + kb + sr0 * 64 + sc8);
        V = *(const us8*)(vtr + vb + sr0 * SQ + sc8);
        W = *(const us8*)(vti + vb + sr0 * SQ + sc8);
    };
    auto commitT = [&](int slot, const us8& K, const us8& C, const us8& V, const us8& W) {
        const int o = swz8(sr0, sc);
        *(us8*)&TILE[slot][0][o] = K;
        *(us8*)&TILE[slot][1][o] = C;
        *(us8*)&TILE[slot][2][o] = V;
        *(us8*)&TILE[slot][3][o] = W;
    };

    float mreg[2][4], Lp[2][4];
    #pragma unroll
    for (int rs = 0; rs < 2; ++rs)
        #pragma unroll
        for (int r = 0; r < 4; ++r) { mreg[rs][r] = -1e30f; Lp[rs][r] = 0.f; }
    f4 Ovr[2][4], Ovi[2][4];
    #pragma unroll
    for (int rs = 0; rs < 2; ++rs)
        #pragma unroll
        for (int d = 0; d < 4; ++d) { Ovr[rs][d] = (f4)0.f; Ovi[rs][d] = (f4)0.f; }

    // prologue: tiles 0,1 -> slots 0,1; tiles 2,3 in regs
    issueT(0, rKa, rCa, rVa, rWa);
    issueT(1, rKb, rCb, rVb, rWb);
    commitT(0, rKa, rCa, rVa, rWa);
    issueT(2, rKa, rCa, rVa, rWa);
    commitT(1, rKb, rCb, rVb, rWb);
    issueT(3, rKb, rCb, rVb, rWb);
    __syncthreads();

    for (int s = 0; s < 16; ++s) {
        const int myt  = 2 * s + grp;
        const int slot = myt % 3;
        if (s < 15) commitT((2 * s + 2) % 3, rKa, rCa, rVa, rWa);  // tile 2s+2
        if (s < 14) issueT(2 * s + 4, rKa, rCa, rVa, rWa);

        const u16* Kr_ = TILE[slot][0];
        const u16* Ki_ = TILE[slot][1];
        const u16* Vr_ = TILE[slot][2];
        const u16* Vi_ = TILE[slot][3];

        // ---- QK^T (complex magnitude scores), K-frags shared by both rs ----
        float sv[2][4][4];
        #pragma unroll
        for (int nt = 0; nt < 4; ++nt) {
            const int kr = nt * 16 + m;
            h8 k0 = *(const h8*)&Kr_[swz8(kr, quad)];
            h8 k1 = *(const h8*)&Kr_[swz8(kr, quad + 4)];
            h8 c0 = *(const h8*)&Ki_[swz8(kr, quad)];
            h8 c1 = *(const h8*)&Ki_[swz8(kr, quad + 4)];
            h8 nc0 = neg_h8(c0);
            h8 nc1 = neg_h8(c1);
            __builtin_amdgcn_s_setprio(1);
            #pragma unroll
            for (int rs = 0; rs < 2; ++rs) {
                f4 ar = (f4)0.f, ai = (f4)0.f;
                ar = MFMA_F16(Qr0[rs], k0, ar, 0, 0, 0);
                ar = MFMA_F16(Qr1[rs], k1, ar, 0, 0, 0);
                ar = MFMA_F16(Qi0[rs], c0, ar, 0, 0, 0);
                ar = MFMA_F16(Qi1[rs], c1, ar, 0, 0, 0);
                ai = MFMA_F16(Qi0[rs], k0, ai, 0, 0, 0);
                ai = MFMA_F16(Qi1[rs], k1, ai, 0, 0, 0);
                ai = MFMA_F16(Qr0[rs], nc0, ai, 0, 0, 0);
                ai = MFMA_F16(Qr1[rs], nc1, ai, 0, 0, 0);
                #pragma unroll
                for (int r = 0; r < 4; ++r)
                    sv[rs][nt][r] =
                        __builtin_amdgcn_sqrtf(ar[r] * ar[r] + ai[r] * ai[r] + 1e-8f) * 0.125f;
            }
            __builtin_amdgcn_s_setprio(0);
        }

        // ---- exact per-row tile max (16-lane reduce) + T13 defer-max ----
        float rv[2][4];
        bool need = false;
        #pragma unroll
        for (int rs = 0; rs < 2; ++rs)
            #pragma unroll
            for (int r = 0; r < 4; ++r) {
                float x = fmaxf(fmaxf(sv[rs][0][r], sv[rs][1][r]),
                                fmaxf(sv[rs][2][r], sv[rs][3][r]));
                x = fmaxf(x, __shfl_xor(x, 1));
                x = fmaxf(x, __shfl_xor(x, 2));
                x = fmaxf(x, __shfl_xor(x, 4));
                x = fmaxf(x, __shfl_xor(x, 8));
                rv[rs][r] = x;
                need |= (x > mreg[rs][r] + 8.f);
            }
        if (__any(need)) {
            #pragma unroll
            for (int rs = 0; rs < 2; ++rs)
                #pragma unroll
                for (int r = 0; r < 4; ++r) {
                    float mn = fmaxf(mreg[rs][r], rv[rs][r]);
                    float al = __expf(mreg[rs][r] - mn);
                    mreg[rs][r] = mn;
                    Lp[rs][r] *= al;
                    #pragma unroll
                    for (int dt = 0; dt < 4; ++dt) {
                        Ovr[rs][dt][r] *= al; Ovi[rs][dt][r] *= al;
                    }
                }
        }

        // ---- P = exp(s - m) -> Pb (wave-private 32-row stripe) ----
        #pragma unroll
        for (int rs = 0; rs < 2; ++rs)
            #pragma unroll
            for (int r = 0; r < 4; ++r) {
                const int prow = wq * 32 + rs * 16 + quad * 4 + r;
                #pragma unroll
                for (int nt = 0; nt < 4; ++nt) {
                    float p = __expf(sv[rs][nt][r] - mreg[rs][r]);
                    Lp[rs][r] += p;
                    const int col = nt * 16 + m;
                    Pb[swz8(prow, col >> 3) + (col & 7)] = f2h(p);
                }
            }

        h8 pa0[2], pa1[2];
        #pragma unroll
        for (int rs = 0; rs < 2; ++rs) {
            const int qrow = wq * 32 + rs * 16 + m;
            pa0[rs] = *(const h8*)&Pb[swz8(qrow, quad)];
            pa1[rs] = *(const h8*)&Pb[swz8(qrow, quad + 4)];
        }

        // ---- PV: V-frags shared by both rs ----
        #pragma unroll
        for (int dt = 0; dt < 4; ++dt) {
            const int vrr = dt * 16 + m;
            h8 b0 = *(const h8*)&Vr_[swz8(vrr, quad)];
            h8 b1 = *(const h8*)&Vr_[swz8(vrr, quad + 4)];
            h8 d0 = *(const h8*)&Vi_[swz8(vrr, quad)];
            h8 d1 = *(const h8*)&Vi_[swz8(vrr, quad + 4)];
            __builtin_amdgcn_s_setprio(1);
            #pragma unroll
            for (int rs = 0; rs < 2; ++rs) {
                Ovr[rs][dt] = MFMA_F16(pa0[rs], b0, Ovr[rs][dt], 0, 0, 0);
                Ovr[rs][dt] = MFMA_F16(pa1[rs], b1, Ovr[rs][dt], 0, 0, 0);
                Ovi[rs][dt] = MFMA_F16(pa0[rs], d0, Ovi[rs][dt], 0, 0, 0);
                Ovi[rs][dt] = MFMA_F16(pa1[rs], d1, Ovi[rs][dt], 0, 0, 0);
            }
            __builtin_amdgcn_s_setprio(0);
        }

        __syncthreads();                 // my slot free; commits visible next iter
        if (s < 15) commitT((2 * s + 3) % 3, rKb, rCb, rVb, rWb);  // tile 2s+3
        if (s < 14) issueT(2 * s + 5, rKb, rCb, rVb, rWb);
        __syncthreads();
    }

    // ---- cross-group merge: B -> LDS scratch, A merges + stores ----
    float* scr = (float*)&TILE[0][0][0];          // 80KB used of 96KB
    const int sbase = ((wq & 3) * 64 + l) * 80;
    if (grp == 1) {
        #pragma unroll
        for (int rs = 0; rs < 2; ++rs) {
            #pragma unroll
            for (int dt = 0; dt < 4; ++dt)
                #pragma unroll
                for (int r = 0; r < 4; ++r) {
                    scr[sbase + rs * 32 + dt * 8 + r * 2 + 0] = Ovr[rs][dt][r];
                    scr[sbase + rs * 32 + dt * 8 + r * 2 + 1] = Ovi[rs][dt][r];
                }
            #pragma unroll
            for (int r = 0; r < 4; ++r) {
                scr[sbase + 64 + rs * 8 + r * 2 + 0] = mreg[rs][r];
                scr[sbase + 64 + rs * 8 + r * 2 + 1] = Lp[rs][r];
            }
        }
    }
    __syncthreads();
    if (grp == 0) {
        u16* Dr = br ? o2r : o1r;
        u16* Di = br ? o2i : o1i;
        #pragma unroll
        for (int rs = 0; rs < 2; ++rs) {
            float inv[4];
            #pragma unroll
            for (int r = 0; r < 4; ++r) {
                float mB = scr[sbase + 64 + rs * 8 + r * 2 + 0];
                float LB = scr[sbase + 64 + rs * 8 + r * 2 + 1];
                float mn = fmaxf(mreg[rs][r], mB);
                float aA = __expf(mreg[rs][r] - mn);
                float aB = __expf(mB - mn);
                float Lm = Lp[rs][r] * aA + LB * aB;
                #pragma unroll
                for (int dt = 0; dt < 4; ++dt) {
                    float obr_ = scr[sbase + rs * 32 + dt * 8 + r * 2 + 0];
                    float obi_ = scr[sbase + rs * 32 + dt * 8 + r * 2 + 1];
                    Ovr[rs][dt][r] = Ovr[rs][dt][r] * aA + obr_ * aB;
                    Ovi[rs][dt][r] = Ovi[rs][dt][r] * aA + obi_ * aB;
                }
                // reduce merged L across the 16 m-lanes
                float x = Lm;
                x += __shfl_xor(x, 1);
                x += __shfl_xor(x, 2);
                x += __shfl_xor(x, 4);
                x += __shfl_xor(x, 8);
                inv[r] = 1.f / x;
            }
            #pragma unroll
            for (int dt = 0; dt < 4; ++dt) {
                #pragma unroll
                for (int r = 0; r < 4; ++r) {
                    int q = rh * 32 + rs * 16 + quad * 4 + r;
                    Dr[qbase + q * 64 + dt * 16 + m] = f2h(Ovr[rs][dt][r] * inv[r]);
                    Di[qbase + q * 64 + dt * 16 + m] = f2h(Ovi[rs][dt][r] * inv[r]);
                }
            }
        }
    }
}

// ---------------------------------------------------------------------------
// Kernel 3: MFMA epilogue (unchanged from R6).
// ---------------------------------------------------------------------------
__global__ __launch_bounds__(256) void epi_kernel(
    const u16* __restrict__ o1r, const u16* __restrict__ o1i,
    const u16* __restrict__ o2r, const u16* __restrict__ o2i,
    const float* __restrict__ out_gr, const float* __restrict__ out_gi,
    const float* __restrict__ subw,
    const u16* __restrict__ pko,
    const float* __restrict__ obr, const float* __restrict__ obi,
    float* __restrict__ out_r, float* __restrict__ out_i)
{
    __shared__ __align__(16) u16 L1r[16][64], L1i[16][64];
    __shared__ __align__(16) u16 L2r[16][64], L2i[16][64];
    __shared__ __align__(16) u16 Xr[16 * 64], Xi[16 * 64];

    const int t = threadIdx.x;
    const int rowbase = blockIdx.x * 16;

    {
        int r = t >> 4, c4 = (t & 15) * 4;
        size_t gi = (size_t)(rowbase + r) * 64 + c4;
        *(us4v*)&L1r[r][c4] = *(const us4v*)(o1r + gi);
        *(us4v*)&L1i[r][c4] = *(const us4v*)(o1i + gi);
        *(us4v*)&L2r[r][c4] = *(const us4v*)(o2r + gi);
        *(us4v*)&L2i[r][c4] = *(const us4v*)(o2i + gi);
    }
    __syncthreads();

    {
        int r = t >> 4, c4 = (t & 15) * 4;
        float ss = 0.f;
        #pragma unroll
        for (int j = 0; j < 4; ++j) {
            float a = h2f(L1r[r][c4 + j]), b = h2f(L1i[r][c4 + j]);
            float c = h2f(L2r[r][c4 + j]), d = h2f(L2i[r][c4 + j]);
            ss += a * a + b * b + c * c + d * d;
        }
        ss += __shfl_xor(ss, 1);
        ss += __shfl_xor(ss, 2);
        ss += __shfl_xor(ss, 4);
        ss += __shfl_xor(ss, 8);
        float inv = 1.f / sqrtf(ss * (1.f / 128.f) + 1e-5f);

        float4 g_r = *(const float4*)(out_gr + (size_t)(rowbase + r) * 64 + c4);
        float4 g_i = *(const float4*)(out_gi + (size_t)(rowbase + r) * 64 + c4);
        const float* grv = (const float*)&g_r;
        const float* giv = (const float*)&g_i;

        us4v xrp, xip;
        #pragma unroll
        for (int j = 0; j < 4; ++j) {
            int c = c4 + j;
            int s = c >> 1;
            float cr_ = (c & 1) ? h2f(L2r[r][s]) : h2f(L1r[r][s]);
            float ci_ = (c & 1) ? h2f(L2i[r][s]) : h2f(L1i[r][s]);
            float sw = subw[c];
            float ar_ = cr_ * inv * sw;
            float ai_ = ci_ * inv * sw;
            xrp[j] = f2h(grv[j] * ar_ - giv[j] * ai_);
            xip[j] = f2h(grv[j] * ai_ + giv[j] * ar_);
        }
        const int off = swz8(r, c4 >> 3) + (c4 & 7);
        *(us4v*)&Xr[off] = xrp;
        *(us4v*)&Xi[off] = xip;
    }
    __syncthreads();

    const int wv = t >> 6, l = t & 63;
    const int quad = l >> 4, m16 = l & 15;
    const int l8 = l * 8;

    h8 Ar0 = *(const h8*)&Xr[swz8(m16, quad)];
    h8 Ar1 = *(const h8*)&Xr[swz8(m16, quad + 4)];
    h8 Ai0 = *(const h8*)&Xi[swz8(m16, quad)];
    h8 Ai1 = *(const h8*)&Xi[swz8(m16, quad + 4)];
    h8 nAi0 = neg_h8(Ai0), nAi1 = neg_h8(Ai1);

    const int c = wv * 16 + m16;
    h8 Br0 = *(const h8*)(pko + wv * 1024 + l8);
    h8 Br1 = *(const h8*)(pko + wv * 1024 + 512 + l8);
    h8 Bi0 = *(const h8*)(pko + 4096 + wv * 1024 + l8);
    h8 Bi1 = *(const h8*)(pko + 4096 + wv * 1024 + 512 + l8);

    f4 Cr = (f4)0.f, Ci = (f4)0.f;
    Cr = MFMA_F16(Ar0,  Br0, Cr, 0, 0, 0);
    Cr = MFMA_F16(Ar1,  Br1, Cr, 0, 0, 0);
    Cr = MFMA_F16(nAi0, Bi0, Cr, 0, 0, 0);
    Cr = MFMA_F16(nAi1, Bi1, Cr, 0, 0, 0);
    Ci = MFMA_F16(Ar0,  Bi0, Ci, 0, 0, 0);
    Ci = MFMA_F16(Ar1,  Bi1, Ci, 0, 0, 0);
    Ci = MFMA_F16(Ai0,  Br0, Ci, 0, 0, 0);
    Ci = MFMA_F16(Ai1,  Br1, Ci, 0, 0, 0);

    float br_ = obr[c], bi_ = obi[c];
    #pragma unroll
    for (int r = 0; r < 4; ++r) {
        size_t g = (size_t)(rowbase + quad * 4 + r) * 64 + c;
        out_r[g] = Cr[r] + br_;
        out_i[g] = Ci[r] + bi_;
    }
}

// ---------------------------------------------------------------------------
extern "C" void kernel_launch(void* const* d_in, const int* in_sizes, int n_in,
                              void* d_out, int out_size, void* d_ws, size_t ws_size,
                              hipStream_t stream)
{
    (void)in_sizes; (void)n_in; (void)out_size; (void)ws_size;

    float* out    = (float*)d_out;
    float* out_r  = out;
    float* out_i  = out + (size_t)NTOT;
    float* out_gr = out + 2 * (size_t)NTOT;
    float* out_gi = out + 3 * (size_t)NTOT;

    char* w = (char*)d_ws;
    const size_t N = (size_t)NTOT;
    u16* q1r = (u16*)w; w += N * 2;
    u16* q1i = (u16*)w; w += N * 2;
    u16* q2r = (u16*)w; w += N * 2;
    u16* q2i = (u16*)w; w += N * 2;
    u16* kpr = (u16*)w; w += N * 2;
    u16* kpi = (u16*)w; w += N * 2;
    u16* vtr = (u16*)w; w += N * 2;   // [h][d][s]
    u16* vti = (u16*)w; w += N * 2;   // [h][d][s]
    u16* o1r = (u16*)w; w += N * 2;
    u16* o1i = (u16*)w; w += N * 2;
    u16* o2r = (u16*)w; w += N * 2;
    u16* o2i = (u16*)w; w += N * 2;

    u16* pk1 = o1r;   // dead until attn writes o1r
    u16* pk2 = q1r;   // dead after attn

    prep1_kernel<<<dim3(40), dim3(128), 0, stream>>>(
        (const float*)d_in[10], (const float*)d_in[11],
        (const float*)d_in[14], (const float*)d_in[15],
        (const float*)d_in[18], (const float*)d_in[19],
        (const float*)d_in[22], (const float*)d_in[23],
        pk1);

    proj_kernel<<<dim3(1024), dim3(256), 0, stream>>>(
        (const float*)d_in[0], (const float*)d_in[1],
        (const float*)d_in[2], (const float*)d_in[3],
        (const float*)d_in[4], (const float*)d_in[5],
        (const float*)d_in[6], (const float*)d_in[7],
        (const float*)d_in[8], (const float*)d_in[9],
        pk1,
        (const float*)d_in[12], (const float*)d_in[13],
        (const float*)d_in[16], (const float*)d_in[17],
        (const float*)d_in[20], (const float*)d_in[21],
        (const float*)d_in[24], (const float*)d_in[25],
        q1r, q1i, q2r, q2i, kpr, kpi, vtr, vti, out_gr, out_gi);

    attn_kernel<<<dim3(SQ / 64, 1, NH), dim3(512), 0, stream>>>(
        q1r, q1i, q2r, q2i, kpr, kpi, vtr, vti, o1r, o1i, o2r, o2i);

    prep2_kernel<<<dim3(8), dim3(128), 0, stream>>>(
        (const float*)d_in[26], (const float*)d_in[27], pk2);

    epi_kernel<<<dim3(1024), dim3(256), 0, stream>>>(
        o1r, o1i, o2r, o2i, out_gr, out_gi,
        (const float*)d_in[34], pk2,
        (const float*)d_in[28], (const float*)d_in[29],
        out_r, out_i);
}

// Round 8
// 234.644 us; speedup vs baseline: 1.2096x; 1.2096x over previous
//
#include <hip/hip_runtime.h>
#include <hip/hip_bf16.h>

#define NH 8
#define SQ 2048
#define HD 64
#define NTOT (NH * SQ * HD)   // 1048576

typedef unsigned short u16;
typedef unsigned int u32;
typedef __attribute__((ext_vector_type(8))) unsigned short us8;
typedef __attribute__((ext_vector_type(4))) unsigned short us4v;
typedef __attribute__((ext_vector_type(8))) _Float16 h8;   // MFMA f16 A/B fragment
typedef __attribute__((ext_vector_type(4))) float f4;      // MFMA C/D fragment
typedef __attribute__((ext_vector_type(4))) u32 u4;

#define MFMA_F16 __builtin_amdgcn_mfma_f32_16x16x32_f16

__device__ __forceinline__ u16 f2h(float f) {
    union { _Float16 h; u16 u; } c; c.h = (_Float16)f; return c.u;
}
__device__ __forceinline__ float h2f(u16 u) {
    union { _Float16 h; u16 u; } c; c.u = u; return (float)c.h;
}
__device__ __forceinline__ h8 neg_h8(h8 a) {
    union { h8 h; u4 u; } c; c.h = a;
    c.u ^= 0x80008000u;
    return c.h;
}
// 8 contiguous f32 -> f16x8 fragment (two float4 loads, hw cvt)
__device__ __forceinline__ h8 pack8h(const float* p) {
    float4 a = ((const float4*)p)[0];
    float4 b = ((const float4*)p)[1];
    h8 r;
    r[0] = (_Float16)a.x; r[1] = (_Float16)a.y; r[2] = (_Float16)a.z; r[3] = (_Float16)a.w;
    r[4] = (_Float16)b.x; r[5] = (_Float16)b.y; r[6] = (_Float16)b.z; r[7] = (_Float16)b.w;
    return r;
}

// T2 swizzle: pitch 64 u16 (128B rows), 16B-chunk index XOR'd with row&7.
__device__ __forceinline__ int swz8(int row, int chunk) {   // u16 offset of 8-u16 chunk
    return row * 64 + ((chunk ^ (row & 7)) << 3);
}

struct Afrag { h8 r0, r1, i0, i1, ni0, ni1; };

// ---------------------------------------------------------------------------
// Prep kernel: pack ALL weights into MFMA B-fragment planes (2KB each).
// Planes: qwr 0-7, qwi 8-15, kwr 16-19, kwi 20-23, vwr 24-27, vwi 28-31,
//         gwr 32-35, gwi 36-39, owr 40-43, owi 44-47.
// ---------------------------------------------------------------------------
__global__ __launch_bounds__(128) void prep_kernel(
    const float* __restrict__ qwr, const float* __restrict__ qwi,
    const float* __restrict__ kwr, const float* __restrict__ kwi,
    const float* __restrict__ vwr, const float* __restrict__ vwi,
    const float* __restrict__ gwr, const float* __restrict__ gwi,
    const float* __restrict__ owr, const float* __restrict__ owi,
    u16* __restrict__ pk)
{
    const int b = blockIdx.x;
    const float* W; int nt;
    if (b < 8)       { W = qwr; nt = b; }
    else if (b < 16) { W = qwi; nt = b - 8; }
    else if (b < 20) { W = kwr; nt = b - 16; }
    else if (b < 24) { W = kwi; nt = b - 20; }
    else if (b < 28) { W = vwr; nt = b - 24; }
    else if (b < 32) { W = vwi; nt = b - 28; }
    else if (b < 36) { W = gwr; nt = b - 32; }
    else if (b < 40) { W = gwi; nt = b - 36; }
    else if (b < 44) { W = owr; nt = b - 40; }
    else             { W = owi; nt = b - 44; }
    const int t = threadIdx.x, hf = t >> 6, l = t & 63;
    const int quad = l >> 4, m16 = l & 15;
    h8 v = pack8h(W + (nt * 16 + m16) * 64 + hf * 32 + quad * 8);
    *(h8*)(pk + b * 1024 + hf * 512 + l * 8) = v;
}

// ---------------------------------------------------------------------------
// Kernel 1: MFMA complex projections (unchanged from R6).
// ---------------------------------------------------------------------------
__global__ __launch_bounds__(256) void proj_kernel(
    const float* __restrict__ q_r, const float* __restrict__ q_i,
    const float* __restrict__ k_r, const float* __restrict__ k_i,
    const float* __restrict__ v_r, const float* __restrict__ v_i,
    const float* __restrict__ pe_q_r, const float* __restrict__ pe_q_i,
    const float* __restrict__ pe_k_r, const float* __restrict__ pe_k_i,
    const u16* __restrict__ pk,
    const float* __restrict__ qbr, const float* __restrict__ qbi,
    const float* __restrict__ kbr, const float* __restrict__ kbi,
    const float* __restrict__ vbr, const float* __restrict__ vbi,
    const float* __restrict__ gbr, const float* __restrict__ gbi,
    u16* __restrict__ q1r, u16* __restrict__ q1i,
    u16* __restrict__ q2r, u16* __restrict__ q2i,
    u16* __restrict__ kpr, u16* __restrict__ kpi,
    u16* __restrict__ vtr, u16* __restrict__ vti,
    float* __restrict__ out_gr, float* __restrict__ out_gi)
{
    __shared__ __align__(16) u16 Sqr[16 * 64], Sqi[16 * 64];
    __shared__ __align__(16) u16 Skr[16 * 64], Ski[16 * 64];
    __shared__ __align__(16) u16 Svr[16 * 64], Svi[16 * 64];

    const int t = threadIdx.x;
    const int wv = t >> 6, l = t & 63;
    const int quad = l >> 4, m16 = l & 15;
    const int rowbase = blockIdx.x * 16;
    const int h = rowbase >> 11;
    const int l8 = l * 8;

    // ---- stage 6 input tiles: coalesced float4 -> f16 -> swz8 LDS ----
    {
        const int r = t >> 4, c4 = (t & 15) * 4;
        const int off = swz8(r, c4 >> 3) + (c4 & 7);
        const size_t gi = (size_t)(rowbase + r) * 64 + c4;
        auto stage = [&](const float* src, u16* dst) {
            float4 v = *(const float4*)(src + gi);
            us4v p;
            p[0] = f2h(v.x); p[1] = f2h(v.y); p[2] = f2h(v.z); p[3] = f2h(v.w);
            *(us4v*)&dst[off] = p;
        };
        stage(q_r, Sqr); stage(q_i, Sqi);
        stage(k_r, Skr); stage(k_i, Ski);
        stage(v_r, Svr); stage(v_i, Svi);
    }
    __syncthreads();

    auto loadA = [&](const u16* Sr, const u16* Si) {
        Afrag a;
        a.r0 = *(const h8*)&Sr[swz8(m16, quad)];
        a.r1 = *(const h8*)&Sr[swz8(m16, quad + 4)];
        a.i0 = *(const h8*)&Si[swz8(m16, quad)];
        a.i1 = *(const h8*)&Si[swz8(m16, quad + 4)];
        a.ni0 = neg_h8(a.i0);
        a.ni1 = neg_h8(a.i1);
        return a;
    };

    auto ctile = [&](const Afrag& A, int planeR, int planeI, f4& Cr, f4& Ci) {
        const u16* pR = pk + planeR * 1024;
        const u16* pI = pk + planeI * 1024;
        h8 Br0 = *(const h8*)(pR + l8);
        h8 Br1 = *(const h8*)(pR + 512 + l8);
        h8 Bi0 = *(const h8*)(pI + l8);
        h8 Bi1 = *(const h8*)(pI + 512 + l8);
        Cr = (f4)0.f; Ci = (f4)0.f;
        Cr = MFMA_F16(A.r0,  Br0, Cr, 0, 0, 0);
        Cr = MFMA_F16(A.r1,  Br1, Cr, 0, 0, 0);
        Cr = MFMA_F16(A.ni0, Bi0, Cr, 0, 0, 0);
        Cr = MFMA_F16(A.ni1, Bi1, Cr, 0, 0, 0);
        Ci = MFMA_F16(A.r0,  Bi0, Ci, 0, 0, 0);
        Ci = MFMA_F16(A.r1,  Bi1, Ci, 0, 0, 0);
        Ci = MFMA_F16(A.i0,  Br0, Ci, 0, 0, 0);
        Ci = MFMA_F16(A.i1,  Br1, Ci, 0, 0, 0);
    };

    auto qtile = [&](const Afrag& A, int nt) {
        f4 Cr, Ci;
        ctile(A, nt, 8 + nt, Cr, Ci);
        int c = nt * 16 + m16;
        float br = qbr[c], bi = qbi[c];
        int dd = c >> 1, pc = c & 63;
        u16* dR = (c & 1) ? q2r : q1r;
        u16* dI = (c & 1) ? q2i : q1i;
        #pragma unroll
        for (int r = 0; r < 4; ++r) {
            int g = rowbase + quad * 4 + r;
            dR[g * 64 + dd] = f2h(Cr[r] + br + pe_q_r[g * 64 + pc]);
            dI[g * 64 + dd] = f2h(Ci[r] + bi + pe_q_i[g * 64 + pc]);
        }
    };
    auto ktile = [&](const Afrag& A, int nt) {
        f4 Cr, Ci;
        ctile(A, 16 + nt, 20 + nt, Cr, Ci);
        int c = nt * 16 + m16;
        float br = kbr[c], bi = kbi[c];
        #pragma unroll
        for (int r = 0; r < 4; ++r) {
            int g = rowbase + quad * 4 + r;
            kpr[g * 64 + c] = f2h(Cr[r] + br + pe_k_r[g * 64 + c]);
            kpi[g * 64 + c] = f2h(Ci[r] + bi + pe_k_i[g * 64 + c]);
        }
    };
    auto vtile = [&](const Afrag& A, int nt) {
        f4 Cr, Ci;
        ctile(A, 24 + nt, 28 + nt, Cr, Ci);
        int c = nt * 16 + m16;
        float br = vbr[c], bi = vbi[c];
        int s0 = (rowbase & 2047) + quad * 4;
        size_t tix = (size_t)(h * 64 + c) * 2048 + s0;
        us4v pr, pi;
        #pragma unroll
        for (int r = 0; r < 4; ++r) {
            pr[r] = f2h(Cr[r] + br);
            pi[r] = f2h(Ci[r] + bi);
        }
        *(us4v*)&vtr[tix] = pr;
        *(us4v*)&vti[tix] = pi;
    };
    auto gtile = [&](const Afrag& A, int nt) {
        f4 Cr, Ci;
        ctile(A, 32 + nt, 36 + nt, Cr, Ci);
        int c = nt * 16 + m16;
        float br = gbr[c], bi = gbi[c];
        #pragma unroll
        for (int r = 0; r < 4; ++r) {
            int g = rowbase + quad * 4 + r;
            out_gr[g * 64 + c] = Cr[r] + br;
            out_gi[g * 64 + c] = Ci[r] + bi;
        }
    };

    if (wv == 0) {
        Afrag Aq = loadA(Sqr, Sqi);
        qtile(Aq, 0); qtile(Aq, 1); qtile(Aq, 2); qtile(Aq, 3); qtile(Aq, 4);
    } else if (wv == 1) {
        Afrag Aq = loadA(Sqr, Sqi);
        qtile(Aq, 5); qtile(Aq, 6); qtile(Aq, 7);
        gtile(Aq, 0); gtile(Aq, 1);
    } else if (wv == 2) {
        Afrag Ak = loadA(Skr, Ski);
        ktile(Ak, 0); ktile(Ak, 1); ktile(Ak, 2); ktile(Ak, 3);
        Afrag Aq = loadA(Sqr, Sqi);
        gtile(Aq, 2);
    } else {
        Afrag Av = loadA(Svr, Svi);
        vtile(Av, 0); vtile(Av, 1); vtile(Av, 2); vtile(Av, 3);
        Afrag Aq = loadA(Sqr, Sqi);
        gtile(Aq, 3);
    }
}

// ---------------------------------------------------------------------------
// Kernel 2: MFMA flash attention + FUSED epilogue (RMS + gate + out-proj).
//   K-loop identical to the verified R5 structure (87.7us): merged branches,
//   512-thread block, dbuf K/V, one barrier/kt. R7's split-K reverted
//   (VGPR-cap spill: WRITE_SIZE 8->35MB).
//   Fused epilogue: block holds o1 (waves 0-3) AND o2 (waves 4-7) for its
//   64 rows -> joint RMS via 512B LDS exchange; X (gated) built in freed Pb;
//   out-proj from packed ow planes 40-47. Kills the o1..o2i 16MB HBM
//   round-trip, the epi kernel, and the prep2 kernel.
// ---------------------------------------------------------------------------
__global__ __launch_bounds__(512, 1) void attn_kernel(
    const u16* __restrict__ q1r, const u16* __restrict__ q1i,
    const u16* __restrict__ q2r, const u16* __restrict__ q2i,
    const u16* __restrict__ kpr, const u16* __restrict__ kpi,
    const u16* __restrict__ vtr, const u16* __restrict__ vti,
    const u16* __restrict__ pk,
    const float* __restrict__ subw,
    const float* __restrict__ obr, const float* __restrict__ obi,
    const float* __restrict__ out_gr, const float* __restrict__ out_gi,
    float* __restrict__ out_r, float* __restrict__ out_i)
{
    __shared__ __align__(16) u16 Kr[2][64 * 64], Ki[2][64 * 64];
    __shared__ __align__(16) u16 Vr[2][64 * 64], Vi[2][64 * 64];
    __shared__ __align__(16) u16 Pb[128 * 64];
    __shared__ float ssL[2][64];

    const int t  = threadIdx.x;      // 0..511
    const int qt = blockIdx.x;
    const int h  = blockIdx.z;

    const int wq   = t >> 6;         // wave 0..7
    const int br   = wq >> 2;        // branch
    const int wr   = wq & 3;         // 16-row block within the 64-row q tile
    const int l    = t & 63;
    const int quad = l >> 4;
    const int m    = l & 15;

    const u16* Qsr = br ? q2r : q1r;
    const u16* Qsi = br ? q2i : q1i;
    const int hbase = h * SQ * 64;
    const int qbase = hbase + qt * 64 * 64;
    const int vbase = h * 64 * SQ;

    const u16* qrr = Qsr + qbase + (wr * 16 + m) * 64;
    const u16* qri = Qsi + qbase + (wr * 16 + m) * 64;
    h8 Qr0 = *(const h8*)(qrr + quad * 8);
    h8 Qr1 = *(const h8*)(qrr + 32 + quad * 8);
    h8 Qi0 = *(const h8*)(qri + quad * 8);
    h8 Qi1 = *(const h8*)(qri + 32 + quad * 8);
    h8 nQr0 = neg_h8(Qr0);
    h8 nQr1 = neg_h8(Qr1);

    // ---- staging: 512 threads cover one 64x64 u16 tile per array ----
    const int sr0 = t >> 3;           // row 0..63
    const int sc  = t & 7;            // 8-u16 chunk
    us8 rK, rC, rV, rW;

    auto issue = [&](int kt) {
        const int kb = hbase + kt * 4096;
        const int vb = vbase + kt * 64;
        const int sc8 = sc * 8;
        rK = *(const us8*)(kpr + kb + sr0 * 64 + sc8);
        rC = *(const us8*)(kpi + kb + sr0 * 64 + sc8);
        rV = *(const us8*)(vtr + vb + sr0 * SQ + sc8);
        rW = *(const us8*)(vti + vb + sr0 * SQ + sc8);
    };
    auto commit = [&](int b) {
        const int o = swz8(sr0, sc);
        *(us8*)&Kr[b][o] = rK;
        *(us8*)&Ki[b][o] = rC;
        *(us8*)&Vr[b][o] = rV;
        *(us8*)&Vi[b][o] = rW;
    };

    float mreg[4], Lp[4];
    #pragma unroll
    for (int r = 0; r < 4; ++r) { mreg[r] = -1e30f; Lp[r] = 0.f; }
    f4 Ovr[4], Ovi[4];
    #pragma unroll
    for (int d = 0; d < 4; ++d) { Ovr[d] = (f4)0.f; Ovi[d] = (f4)0.f; }

    // prologue: tile0 -> buf0; loads for tile1 in flight
    issue(0);
    commit(0);          // compiler inserts vmcnt wait
    issue(1);
    __syncthreads();

    for (int kt = 0; kt < 32; ++kt) {
        const int cur = kt & 1;
        if (kt < 31) commit(cur ^ 1);    // tile kt+1 regs -> other buffer
        if (kt < 30) issue(kt + 2);      // loads in flight across this iter

        // ---- QK^T (complex magnitude scores) ----
        float sv[4][4];
        #pragma unroll
        for (int nt = 0; nt < 4; ++nt) {
            const int kr = nt * 16 + m;
            h8 k0 = *(const h8*)&Kr[cur][swz8(kr, quad)];
            h8 k1 = *(const h8*)&Kr[cur][swz8(kr, quad + 4)];
            h8 c0 = *(const h8*)&Ki[cur][swz8(kr, quad)];
            h8 c1 = *(const h8*)&Ki[cur][swz8(kr, quad + 4)];
            f4 ar = (f4)0.f, ai = (f4)0.f;
            __builtin_amdgcn_s_setprio(1);
            ar = MFMA_F16(Qr0, k0, ar, 0, 0, 0);
            ar = MFMA_F16(Qr1, k1, ar, 0, 0, 0);
            ar = MFMA_F16(Qi0, c0, ar, 0, 0, 0);
            ar = MFMA_F16(Qi1, c1, ar, 0, 0, 0);
            ai = MFMA_F16(Qi0, k0, ai, 0, 0, 0);
            ai = MFMA_F16(Qi1, k1, ai, 0, 0, 0);
            ai = MFMA_F16(nQr0, c0, ai, 0, 0, 0);
            ai = MFMA_F16(nQr1, c1, ai, 0, 0, 0);
            __builtin_amdgcn_s_setprio(0);
            #pragma unroll
            for (int r = 0; r < 4; ++r)
                sv[nt][r] = __builtin_amdgcn_sqrtf(ar[r] * ar[r] + ai[r] * ai[r] + 1e-8f) * 0.125f;
        }

        // ---- exact per-row tile max (16-lane reduce) ----
        float rv[4];
        #pragma unroll
        for (int r = 0; r < 4; ++r) {
            float x = fmaxf(fmaxf(sv[0][r], sv[1][r]), fmaxf(sv[2][r], sv[3][r]));
            x = fmaxf(x, __shfl_xor(x, 1));
            x = fmaxf(x, __shfl_xor(x, 2));
            x = fmaxf(x, __shfl_xor(x, 4));
            x = fmaxf(x, __shfl_xor(x, 8));
            rv[r] = x;
        }

        // ---- T13 defer-max: rescale only when a row grows past slack ----
        bool need = (rv[0] > mreg[0] + 8.f) | (rv[1] > mreg[1] + 8.f) |
                    (rv[2] > mreg[2] + 8.f) | (rv[3] > mreg[3] + 8.f);
        if (__any(need)) {
            #pragma unroll
            for (int r = 0; r < 4; ++r) {
                float mn = fmaxf(mreg[r], rv[r]);
                float al = __expf(mreg[r] - mn);
                mreg[r] = mn;
                Lp[r] *= al;
                #pragma unroll
                for (int dtr = 0; dtr < 4; ++dtr) { Ovr[dtr][r] *= al; Ovi[dtr][r] *= al; }
            }
        }

        // ---- P = exp(s - m)  (f32 row-sum partials; f16 to LDS for MFMA) ----
        #pragma unroll
        for (int r = 0; r < 4; ++r) {
            const int prow = wq * 16 + quad * 4 + r;
            #pragma unroll
            for (int nt = 0; nt < 4; ++nt) {
                float p = __expf(sv[nt][r] - mreg[r]);
                Lp[r] += p;
                const int col = nt * 16 + m;
                Pb[swz8(prow, col >> 3) + (col & 7)] = f2h(p);
            }
        }

        const int qrow = wq * 16 + m;
        h8 pa0 = *(const h8*)&Pb[swz8(qrow, quad)];
        h8 pa1 = *(const h8*)&Pb[swz8(qrow, quad + 4)];

        // ---- PV ----
        #pragma unroll
        for (int dt = 0; dt < 4; ++dt) {
            const int vr_ = dt * 16 + m;
            h8 b0 = *(const h8*)&Vr[cur][swz8(vr_, quad)];
            h8 b1 = *(const h8*)&Vr[cur][swz8(vr_, quad + 4)];
            h8 d0 = *(const h8*)&Vi[cur][swz8(vr_, quad)];
            h8 d1 = *(const h8*)&Vi[cur][swz8(vr_, quad + 4)];
            __builtin_amdgcn_s_setprio(1);
            Ovr[dt] = MFMA_F16(pa0, b0, Ovr[dt], 0, 0, 0);
            Ovr[dt] = MFMA_F16(pa1, b1, Ovr[dt], 0, 0, 0);
            Ovi[dt] = MFMA_F16(pa0, d0, Ovi[dt], 0, 0, 0);
            Ovi[dt] = MFMA_F16(pa1, d1, Ovi[dt], 0, 0, 0);
            __builtin_amdgcn_s_setprio(0);
        }

        __syncthreads();    // buf cur consumed; buf cur^1 fully written
    }

    // =======================================================================
    // Fused epilogue: L-normalize -> joint RMS -> gate -> out-projection.
    // =======================================================================
    {
        // finish L across the 16 m-lanes; normalize O in f32
        #pragma unroll
        for (int r = 0; r < 4; ++r) {
            float x = Lp[r];
            x += __shfl_xor(x, 1);
            x += __shfl_xor(x, 2);
            x += __shfl_xor(x, 4);
            x += __shfl_xor(x, 8);
            float inv = 1.f / x;
            #pragma unroll
            for (int dt = 0; dt < 4; ++dt) { Ovr[dt][r] *= inv; Ovi[dt][r] *= inv; }
        }

        // per-row sum of squares over this wave's 64 cols (one branch, r+i)
        float ssp[4];
        #pragma unroll
        for (int r = 0; r < 4; ++r) {
            float s = 0.f;
            #pragma unroll
            for (int dt = 0; dt < 4; ++dt)
                s += Ovr[dt][r] * Ovr[dt][r] + Ovi[dt][r] * Ovi[dt][r];
            s += __shfl_xor(s, 1);
            s += __shfl_xor(s, 2);
            s += __shfl_xor(s, 4);
            s += __shfl_xor(s, 8);
            ssp[r] = s;
        }
        if (m == 0) {
            #pragma unroll
            for (int r = 0; r < 4; ++r)
                ssL[br][wr * 16 + quad * 4 + r] = ssp[r];
        }
        __syncthreads();

        // rms^-1 per row (joint over both branches = all 128 interleaved cols)
        float rmi[4];
        #pragma unroll
        for (int r = 0; r < 4; ++r) {
            const int row = wr * 16 + quad * 4 + r;
            float ss = ssL[0][row] + ssL[1][row];
            rmi[r] = 1.f / sqrtf(ss * (1.f / 128.f) + 1e-5f);
        }

        // X = gate(gr,gi) * (norm * subw): cols c = 2*(dt*16+m)+br, dt<2.
        // Written f16 to freed Pb: Xr = Pb[0..4095], Xi = Pb[4096..8191].
        u16* Xr = Pb;
        u16* Xi = Pb + 4096;
        const int growb = h * 2048 + qt * 64;
        #pragma unroll
        for (int dt = 0; dt < 2; ++dt) {
            const int k = dt * 16 + m;
            const int c = 2 * k + br;
            const float sw = subw[c];
            #pragma unroll
            for (int r = 0; r < 4; ++r) {
                const int row = wr * 16 + quad * 4 + r;
                const size_t gidx = (size_t)(growb + row) * 64 + c;
                float g_r = out_gr[gidx];
                float g_i = out_gi[gidx];
                float a_r = Ovr[dt][r] * rmi[r] * sw;
                float a_i = Ovi[dt][r] * rmi[r] * sw;
                const int off = swz8(row, c >> 3) + (c & 7);
                Xr[off] = f2h(g_r * a_r - g_i * a_i);
                Xi[off] = f2h(g_r * a_i + g_i * a_r);
            }
        }
        __syncthreads();

        // out-projection: wave (ct = wq&3, rh2 = wq>>2); 2 row-tiles each.
        const int ct  = wq & 3;
        const int rh2 = wq >> 2;
        const int c   = ct * 16 + m;
        const float br_ = obr[c], bi_ = obi[c];
        const u16* pR = pk + (40 + ct) * 1024;
        const u16* pI = pk + (44 + ct) * 1024;
        h8 Br0 = *(const h8*)(pR + l * 8);
        h8 Br1 = *(const h8*)(pR + 512 + l * 8);
        h8 Bi0 = *(const h8*)(pI + l * 8);
        h8 Bi1 = *(const h8*)(pI + 512 + l * 8);

        #pragma unroll
        for (int rt = 0; rt < 2; ++rt) {
            const int arow = rh2 * 32 + rt * 16 + m;
            h8 Ar0 = *(const h8*)&Xr[swz8(arow, quad)];
            h8 Ar1 = *(const h8*)&Xr[swz8(arow, quad + 4)];
            h8 Ai0 = *(const h8*)&Xi[swz8(arow, quad)];
            h8 Ai1 = *(const h8*)&Xi[swz8(arow, quad + 4)];
            h8 nAi0 = neg_h8(Ai0), nAi1 = neg_h8(Ai1);

            f4 Cr = (f4)0.f, Ci = (f4)0.f;
            Cr = MFMA_F16(Ar0,  Br0, Cr, 0, 0, 0);
            Cr = MFMA_F16(Ar1,  Br1, Cr, 0, 0, 0);
            Cr = MFMA_F16(nAi0, Bi0, Cr, 0, 0, 0);
            Cr = MFMA_F16(nAi1, Bi1, Cr, 0, 0, 0);
            Ci = MFMA_F16(Ar0,  Bi0, Ci, 0, 0, 0);
            Ci = MFMA_F16(Ar1,  Bi1, Ci, 0, 0, 0);
            Ci = MFMA_F16(Ai0,  Br0, Ci, 0, 0, 0);
            Ci = MFMA_F16(Ai1,  Br1, Ci, 0, 0, 0);

            #pragma unroll
            for (int r = 0; r < 4; ++r) {
                const int row = rh2 * 32 + rt * 16 + quad * 4 + r;
                const size_t g = (size_t)(growb + row) * 64 + c;
                out_r[g] = Cr[r] + br_;
                out_i[g] = Ci[r] + bi_;
            }
        }
    }
}

// ---------------------------------------------------------------------------
extern "C" void kernel_launch(void* const* d_in, const int* in_sizes, int n_in,
                              void* d_out, int out_size, void* d_ws, size_t ws_size,
                              hipStream_t stream)
{
    (void)in_sizes; (void)n_in; (void)out_size; (void)ws_size;

    float* out    = (float*)d_out;
    float* out_r  = out;
    float* out_i  = out + (size_t)NTOT;
    float* out_gr = out + 2 * (size_t)NTOT;
    float* out_gi = out + 3 * (size_t)NTOT;

    char* w = (char*)d_ws;
    const size_t N = (size_t)NTOT;
    u16* q1r = (u16*)w; w += N * 2;
    u16* q1i = (u16*)w; w += N * 2;
    u16* q2r = (u16*)w; w += N * 2;
    u16* q2i = (u16*)w; w += N * 2;
    u16* kpr = (u16*)w; w += N * 2;
    u16* kpi = (u16*)w; w += N * 2;
    u16* vtr = (u16*)w; w += N * 2;   // [h][d][s]
    u16* vti = (u16*)w; w += N * 2;   // [h][d][s]
    u16* pk  = (u16*)w;               // 96KB packed weights (former o1r region)

    prep_kernel<<<dim3(48), dim3(128), 0, stream>>>(
        (const float*)d_in[10], (const float*)d_in[11],
        (const float*)d_in[14], (const float*)d_in[15],
        (const float*)d_in[18], (const float*)d_in[19],
        (const float*)d_in[22], (const float*)d_in[23],
        (const float*)d_in[26], (const float*)d_in[27],
        pk);

    proj_kernel<<<dim3(1024), dim3(256), 0, stream>>>(
        (const float*)d_in[0], (const float*)d_in[1],
        (const float*)d_in[2], (const float*)d_in[3],
        (const float*)d_in[4], (const float*)d_in[5],
        (const float*)d_in[6], (const float*)d_in[7],
        (const float*)d_in[8], (const float*)d_in[9],
        pk,
        (const float*)d_in[12], (const float*)d_in[13],
        (const float*)d_in[16], (const float*)d_in[17],
        (const float*)d_in[20], (const float*)d_in[21],
        (const float*)d_in[24], (const float*)d_in[25],
        q1r, q1i, q2r, q2i, kpr, kpi, vtr, vti, out_gr, out_gi);

    attn_kernel<<<dim3(SQ / 64, 1, NH), dim3(512), 0, stream>>>(
        q1r, q1i, q2r, q2i, kpr, kpi, vtr, vti,
        pk, (const float*)d_in[34],
        (const float*)d_in[28], (const float*)d_in[29],
        out_gr, out_gi, out_r, out_i);
}

// Round 10
// 229.965 us; speedup vs baseline: 1.2342x; 1.0203x over previous
//
#include <hip/hip_runtime.h>
#include <hip/hip_bf16.h>

#define NH 8
#define SQ 2048
#define HD 64
#define NTOT (NH * SQ * HD)   // 1048576

typedef unsigned short u16;
typedef unsigned int u32;
typedef __attribute__((ext_vector_type(8))) unsigned short us8;
typedef __attribute__((ext_vector_type(4))) unsigned short us4v;
typedef __attribute__((ext_vector_type(8))) _Float16 h8;   // MFMA f16 A/B fragment
typedef __attribute__((ext_vector_type(4))) float f4;      // MFMA C/D fragment
typedef __attribute__((ext_vector_type(4))) u32 u4;

#define MFMA_F16 __builtin_amdgcn_mfma_f32_16x16x32_f16

__device__ __forceinline__ u16 f2h(float f) {
    union { _Float16 h; u16 u; } c; c.h = (_Float16)f; return c.u;
}
__device__ __forceinline__ float h2f(u16 u) {
    union { _Float16 h; u16 u; } c; c.u = u; return (float)c.h;
}
__device__ __forceinline__ h8 neg_h8(h8 a) {
    union { h8 h; u4 u; } c; c.h = a;
    c.u ^= 0x80008000u;
    return c.h;
}
// 8 contiguous f32 -> f16x8 fragment (two float4 loads, hw cvt)
__device__ __forceinline__ h8 pack8h(const float* p) {
    float4 a = ((const float4*)p)[0];
    float4 b = ((const float4*)p)[1];
    h8 r;
    r[0] = (_Float16)a.x; r[1] = (_Float16)a.y; r[2] = (_Float16)a.z; r[3] = (_Float16)a.w;
    r[4] = (_Float16)b.x; r[5] = (_Float16)b.y; r[6] = (_Float16)b.z; r[7] = (_Float16)b.w;
    return r;
}

// T2 swizzle: pitch 64 u16 (128B rows), 16B-chunk index XOR'd with row&7.
__device__ __forceinline__ int swz8(int row, int chunk) {   // u16 offset of 8-u16 chunk
    return row * 64 + ((chunk ^ (row & 7)) << 3);
}

struct Afrag { h8 r0, r1, i0, i1, ni0, ni1; };

// ---------------------------------------------------------------------------
// Prep kernel: pack ALL weights into MFMA B-fragment planes (2KB each).
// Planes: qwr 0-7, qwi 8-15, kwr 16-19, kwi 20-23, vwr 24-27, vwi 28-31,
//         gwr 32-35, gwi 36-39, owr 40-43, owi 44-47.
// ---------------------------------------------------------------------------
__global__ __launch_bounds__(128) void prep_kernel(
    const float* __restrict__ qwr, const float* __restrict__ qwi,
    const float* __restrict__ kwr, const float* __restrict__ kwi,
    const float* __restrict__ vwr, const float* __restrict__ vwi,
    const float* __restrict__ gwr, const float* __restrict__ gwi,
    const float* __restrict__ owr, const float* __restrict__ owi,
    u16* __restrict__ pk)
{
    const int b = blockIdx.x;
    const float* W; int nt;
    if (b < 8)       { W = qwr; nt = b; }
    else if (b < 16) { W = qwi; nt = b - 8; }
    else if (b < 20) { W = kwr; nt = b - 16; }
    else if (b < 24) { W = kwi; nt = b - 20; }
    else if (b < 28) { W = vwr; nt = b - 24; }
    else if (b < 32) { W = vwi; nt = b - 28; }
    else if (b < 36) { W = gwr; nt = b - 32; }
    else if (b < 40) { W = gwi; nt = b - 36; }
    else if (b < 44) { W = owr; nt = b - 40; }
    else             { W = owi; nt = b - 44; }
    const int t = threadIdx.x, hf = t >> 6, l = t & 63;
    const int quad = l >> 4, m16 = l & 15;
    h8 v = pack8h(W + (nt * 16 + m16) * 64 + hf * 32 + quad * 8);
    *(h8*)(pk + b * 1024 + hf * 512 + l * 8) = v;
}

// ---------------------------------------------------------------------------
// Kernel 1: MFMA complex projections.
//   q/k/g outputs routed through LDS and stored COALESCED (us4v/float4,
//   4 full lines per wave-instr) instead of per-lane scalar u16/f32 at
//   stride 128B (16 partial lines per instr, ~1300 instrs per block).
//   Compute phase math identical (pe/bias in f32 before f16 rounding).
//   V keeps its direct 8B store (transposed layout). LDS 33.3KB.
// ---------------------------------------------------------------------------
__global__ __launch_bounds__(256) void proj_kernel(
    const float* __restrict__ q_r, const float* __restrict__ q_i,
    const float* __restrict__ k_r, const float* __restrict__ k_i,
    const float* __restrict__ v_r, const float* __restrict__ v_i,
    const float* __restrict__ pe_q_r, const float* __restrict__ pe_q_i,
    const float* __restrict__ pe_k_r, const float* __restrict__ pe_k_i,
    const u16* __restrict__ pk,
    const float* __restrict__ qbr, const float* __restrict__ qbi,
    const float* __restrict__ kbr, const float* __restrict__ kbi,
    const float* __restrict__ vbr, const float* __restrict__ vbi,
    const float* __restrict__ gbr, const float* __restrict__ gbi,
    u16* __restrict__ q1r, u16* __restrict__ q1i,
    u16* __restrict__ q2r, u16* __restrict__ q2i,
    u16* __restrict__ kpr, u16* __restrict__ kpi,
    u16* __restrict__ vtr, u16* __restrict__ vti,
    float* __restrict__ out_gr, float* __restrict__ out_gi)
{
    __shared__ __align__(16) u16 Sqr[16 * 64], Sqi[16 * 64];
    __shared__ __align__(16) u16 Skr[16 * 64], Ski[16 * 64];
    __shared__ __align__(16) u16 Svr[16 * 64], Svi[16 * 64];
    // output staging, pitch 68 (8B-aligned rows, ~2-4 way conflicts max)
    __shared__ __align__(16) u16 Oq1r[16 * 68], Oq1i[16 * 68];
    __shared__ __align__(16) u16 Oq2r[16 * 68], Oq2i[16 * 68];
    __shared__ __align__(16) u16 Okr[16 * 68],  Oki[16 * 68];
    __shared__ __align__(16) float Ogr[16 * 68], Ogi[16 * 68];

    const int t = threadIdx.x;
    const int wv = t >> 6, l = t & 63;
    const int quad = l >> 4, m16 = l & 15;
    const int rowbase = blockIdx.x * 16;
    const int h = rowbase >> 11;
    const int l8 = l * 8;

    // ---- stage 6 input tiles: coalesced float4 -> f16 -> swz8 LDS ----
    {
        const int r = t >> 4, c4 = (t & 15) * 4;
        const int off = swz8(r, c4 >> 3) + (c4 & 7);
        const size_t gi = (size_t)(rowbase + r) * 64 + c4;
        auto stage = [&](const float* src, u16* dst) {
            float4 v = *(const float4*)(src + gi);
            us4v p;
            p[0] = f2h(v.x); p[1] = f2h(v.y); p[2] = f2h(v.z); p[3] = f2h(v.w);
            *(us4v*)&dst[off] = p;
        };
        stage(q_r, Sqr); stage(q_i, Sqi);
        stage(k_r, Skr); stage(k_i, Ski);
        stage(v_r, Svr); stage(v_i, Svi);
    }
    __syncthreads();

    auto loadA = [&](const u16* Sr, const u16* Si) {
        Afrag a;
        a.r0 = *(const h8*)&Sr[swz8(m16, quad)];
        a.r1 = *(const h8*)&Sr[swz8(m16, quad + 4)];
        a.i0 = *(const h8*)&Si[swz8(m16, quad)];
        a.i1 = *(const h8*)&Si[swz8(m16, quad + 4)];
        a.ni0 = neg_h8(a.i0);
        a.ni1 = neg_h8(a.i1);
        return a;
    };

    auto ctile = [&](const Afrag& A, int planeR, int planeI, f4& Cr, f4& Ci) {
        const u16* pR = pk + planeR * 1024;
        const u16* pI = pk + planeI * 1024;
        h8 Br0 = *(const h8*)(pR + l8);
        h8 Br1 = *(const h8*)(pR + 512 + l8);
        h8 Bi0 = *(const h8*)(pI + l8);
        h8 Bi1 = *(const h8*)(pI + 512 + l8);
        Cr = (f4)0.f; Ci = (f4)0.f;
        Cr = MFMA_F16(A.r0,  Br0, Cr, 0, 0, 0);
        Cr = MFMA_F16(A.r1,  Br1, Cr, 0, 0, 0);
        Cr = MFMA_F16(A.ni0, Bi0, Cr, 0, 0, 0);
        Cr = MFMA_F16(A.ni1, Bi1, Cr, 0, 0, 0);
        Ci = MFMA_F16(A.r0,  Bi0, Ci, 0, 0, 0);
        Ci = MFMA_F16(A.r1,  Bi1, Ci, 0, 0, 0);
        Ci = MFMA_F16(A.i0,  Br0, Ci, 0, 0, 0);
        Ci = MFMA_F16(A.i1,  Br1, Ci, 0, 0, 0);
    };

    // q/k/g tiles write to LDS (coalesced global store later); v stores direct.
    auto qtile = [&](const Afrag& A, int nt) {
        f4 Cr, Ci;
        ctile(A, nt, 8 + nt, Cr, Ci);
        int c = nt * 16 + m16;
        float br = qbr[c], bi = qbi[c];
        int dd = c >> 1, pc = c & 63;
        u16* dR = (c & 1) ? Oq2r : Oq1r;
        u16* dI = (c & 1) ? Oq2i : Oq1i;
        #pragma unroll
        for (int r = 0; r < 4; ++r) {
            int row = quad * 4 + r;
            int g = rowbase + row;
            dR[row * 68 + dd] = f2h(Cr[r] + br + pe_q_r[g * 64 + pc]);
            dI[row * 68 + dd] = f2h(Ci[r] + bi + pe_q_i[g * 64 + pc]);
        }
    };
    auto ktile = [&](const Afrag& A, int nt) {
        f4 Cr, Ci;
        ctile(A, 16 + nt, 20 + nt, Cr, Ci);
        int c = nt * 16 + m16;
        float br = kbr[c], bi = kbi[c];
        #pragma unroll
        for (int r = 0; r < 4; ++r) {
            int row = quad * 4 + r;
            int g = rowbase + row;
            Okr[row * 68 + c] = f2h(Cr[r] + br + pe_k_r[g * 64 + c]);
            Oki[row * 68 + c] = f2h(Ci[r] + bi + pe_k_i[g * 64 + c]);
        }
    };
    auto vtile = [&](const Afrag& A, int nt) {
        f4 Cr, Ci;
        ctile(A, 24 + nt, 28 + nt, Cr, Ci);
        int c = nt * 16 + m16;
        float br = vbr[c], bi = vbi[c];
        int s0 = (rowbase & 2047) + quad * 4;
        size_t tix = (size_t)(h * 64 + c) * 2048 + s0;
        us4v pr, pi;
        #pragma unroll
        for (int r = 0; r < 4; ++r) {
            pr[r] = f2h(Cr[r] + br);
            pi[r] = f2h(Ci[r] + bi);
        }
        *(us4v*)&vtr[tix] = pr;
        *(us4v*)&vti[tix] = pi;
    };
    auto gtile = [&](const Afrag& A, int nt) {
        f4 Cr, Ci;
        ctile(A, 32 + nt, 36 + nt, Cr, Ci);
        int c = nt * 16 + m16;
        float br = gbr[c], bi = gbi[c];
        #pragma unroll
        for (int r = 0; r < 4; ++r) {
            int row = quad * 4 + r;
            Ogr[row * 68 + c] = Cr[r] + br;
            Ogi[row * 68 + c] = Ci[r] + bi;
        }
    };

    if (wv == 0) {
        Afrag Aq = loadA(Sqr, Sqi);
        qtile(Aq, 0); qtile(Aq, 1); qtile(Aq, 2); qtile(Aq, 3); qtile(Aq, 4);
    } else if (wv == 1) {
        Afrag Aq = loadA(Sqr, Sqi);
        qtile(Aq, 5); qtile(Aq, 6); qtile(Aq, 7);
        gtile(Aq, 0); gtile(Aq, 1);
    } else if (wv == 2) {
        Afrag Ak = loadA(Skr, Ski);
        ktile(Ak, 0); ktile(Ak, 1); ktile(Ak, 2); ktile(Ak, 3);
        Afrag Aq = loadA(Sqr, Sqi);
        gtile(Aq, 2);
    } else {
        Afrag Av = loadA(Svr, Svi);
        vtile(Av, 0); vtile(Av, 1); vtile(Av, 2); vtile(Av, 3);
        Afrag Aq = loadA(Sqr, Sqi);
        gtile(Aq, 3);
    }
    __syncthreads();

    // ---- coalesced store phase: us4v / float4 per thread ----
    {
        const int r = t >> 4, c4 = (t & 15) * 4;
        const size_t gi = (size_t)(rowbase + r) * 64 + c4;
        const int lo = r * 68 + c4;
        *(us4v*)&q1r[gi] = *(const us4v*)&Oq1r[lo];
        *(us4v*)&q1i[gi] = *(const us4v*)&Oq1i[lo];
        *(us4v*)&q2r[gi] = *(const us4v*)&Oq2r[lo];
        *(us4v*)&q2i[gi] = *(const us4v*)&Oq2i[lo];
        *(us4v*)&kpr[gi] = *(const us4v*)&Okr[lo];
        *(us4v*)&kpi[gi] = *(const us4v*)&Oki[lo];
        *(float4*)&out_gr[gi] = *(const float4*)&Ogr[lo];
        *(float4*)&out_gi[gi] = *(const float4*)&Ogi[lo];
    }
}

// ---------------------------------------------------------------------------
// Kernel 2: MFMA flash attention + fused epilogue (unchanged from R8,
// verified 88.7us / absmax 0.0625).
// ---------------------------------------------------------------------------
__global__ __launch_bounds__(512, 1) void attn_kernel(
    const u16* __restrict__ q1r, const u16* __restrict__ q1i,
    const u16* __restrict__ q2r, const u16* __restrict__ q2i,
    const u16* __restrict__ kpr, const u16* __restrict__ kpi,
    const u16* __restrict__ vtr, const u16* __restrict__ vti,
    const u16* __restrict__ pk,
    const float* __restrict__ subw,
    const float* __restrict__ obr, const float* __restrict__ obi,
    const float* __restrict__ out_gr, const float* __restrict__ out_gi,
    float* __restrict__ out_r, float* __restrict__ out_i)
{
    __shared__ __align__(16) u16 Kr[2][64 * 64], Ki[2][64 * 64];
    __shared__ __align__(16) u16 Vr[2][64 * 64], Vi[2][64 * 64];
    __shared__ __align__(16) u16 Pb[128 * 64];
    __shared__ float ssL[2][64];

    const int t  = threadIdx.x;      // 0..511
    const int qt = blockIdx.x;
    const int h  = blockIdx.z;

    const int wq   = t >> 6;         // wave 0..7
    const int br   = wq >> 2;        // branch
    const int wr   = wq & 3;         // 16-row block within the 64-row q tile
    const int l    = t & 63;
    const int quad = l >> 4;
    const int m    = l & 15;

    const u16* Qsr = br ? q2r : q1r;
    const u16* Qsi = br ? q2i : q1i;
    const int hbase = h * SQ * 64;
    const int qbase = hbase + qt * 64 * 64;
    const int vbase = h * 64 * SQ;

    const u16* qrr = Qsr + qbase + (wr * 16 + m) * 64;
    const u16* qri = Qsi + qbase + (wr * 16 + m) * 64;
    h8 Qr0 = *(const h8*)(qrr + quad * 8);
    h8 Qr1 = *(const h8*)(qrr + 32 + quad * 8);
    h8 Qi0 = *(const h8*)(qri + quad * 8);
    h8 Qi1 = *(const h8*)(qri + 32 + quad * 8);
    h8 nQr0 = neg_h8(Qr0);
    h8 nQr1 = neg_h8(Qr1);

    // ---- staging: 512 threads cover one 64x64 u16 tile per array ----
    const int sr0 = t >> 3;           // row 0..63
    const int sc  = t & 7;            // 8-u16 chunk
    us8 rK, rC, rV, rW;

    auto issue = [&](int kt) {
        const int kb = hbase + kt * 4096;
        const int vb = vbase + kt * 64;
        const int sc8 = sc * 8;
        rK = *(const us8*)(kpr + kb + sr0 * 64 + sc8);
        rC = *(const us8*)(kpi + kb + sr0 * 64 + sc8);
        rV = *(const us8*)(vtr + vb + sr0 * SQ + sc8);
        rW = *(const us8*)(vti + vb + sr0 * SQ + sc8);
    };
    auto commit = [&](int b) {
        const int o = swz8(sr0, sc);
        *(us8*)&Kr[b][o] = rK;
        *(us8*)&Ki[b][o] = rC;
        *(us8*)&Vr[b][o] = rV;
        *(us8*)&Vi[b][o] = rW;
    };

    float mreg[4], Lp[4];
    #pragma unroll
    for (int r = 0; r < 4; ++r) { mreg[r] = -1e30f; Lp[r] = 0.f; }
    f4 Ovr[4], Ovi[4];
    #pragma unroll
    for (int d = 0; d < 4; ++d) { Ovr[d] = (f4)0.f; Ovi[d] = (f4)0.f; }

    // prologue: tile0 -> buf0; loads for tile1 in flight
    issue(0);
    commit(0);          // compiler inserts vmcnt wait
    issue(1);
    __syncthreads();

    for (int kt = 0; kt < 32; ++kt) {
        const int cur = kt & 1;
        if (kt < 31) commit(cur ^ 1);    // tile kt+1 regs -> other buffer
        if (kt < 30) issue(kt + 2);      // loads in flight across this iter

        // ---- QK^T (complex magnitude scores) ----
        float sv[4][4];
        #pragma unroll
        for (int nt = 0; nt < 4; ++nt) {
            const int kr = nt * 16 + m;
            h8 k0 = *(const h8*)&Kr[cur][swz8(kr, quad)];
            h8 k1 = *(const h8*)&Kr[cur][swz8(kr, quad + 4)];
            h8 c0 = *(const h8*)&Ki[cur][swz8(kr, quad)];
            h8 c1 = *(const h8*)&Ki[cur][swz8(kr, quad + 4)];
            f4 ar = (f4)0.f, ai = (f4)0.f;
            __builtin_amdgcn_s_setprio(1);
            ar = MFMA_F16(Qr0, k0, ar, 0, 0, 0);
            ar = MFMA_F16(Qr1, k1, ar, 0, 0, 0);
            ar = MFMA_F16(Qi0, c0, ar, 0, 0, 0);
            ar = MFMA_F16(Qi1, c1, ar, 0, 0, 0);
            ai = MFMA_F16(Qi0, k0, ai, 0, 0, 0);
            ai = MFMA_F16(Qi1, k1, ai, 0, 0, 0);
            ai = MFMA_F16(nQr0, c0, ai, 0, 0, 0);
            ai = MFMA_F16(nQr1, c1, ai, 0, 0, 0);
            __builtin_amdgcn_s_setprio(0);
            #pragma unroll
            for (int r = 0; r < 4; ++r)
                sv[nt][r] = __builtin_amdgcn_sqrtf(ar[r] * ar[r] + ai[r] * ai[r] + 1e-8f) * 0.125f;
        }

        // ---- exact per-row tile max (16-lane reduce) ----
        float rv[4];
        #pragma unroll
        for (int r = 0; r < 4; ++r) {
            float x = fmaxf(fmaxf(sv[0][r], sv[1][r]), fmaxf(sv[2][r], sv[3][r]));
            x = fmaxf(x, __shfl_xor(x, 1));
            x = fmaxf(x, __shfl_xor(x, 2));
            x = fmaxf(x, __shfl_xor(x, 4));
            x = fmaxf(x, __shfl_xor(x, 8));
            rv[r] = x;
        }

        // ---- T13 defer-max: rescale only when a row grows past slack ----
        bool need = (rv[0] > mreg[0] + 8.f) | (rv[1] > mreg[1] + 8.f) |
                    (rv[2] > mreg[2] + 8.f) | (rv[3] > mreg[3] + 8.f);
        if (__any(need)) {
            #pragma unroll
            for (int r = 0; r < 4; ++r) {
                float mn = fmaxf(mreg[r], rv[r]);
                float al = __expf(mreg[r] - mn);
                mreg[r] = mn;
                Lp[r] *= al;
                #pragma unroll
                for (int dtr = 0; dtr < 4; ++dtr) { Ovr[dtr][r] *= al; Ovi[dtr][r] *= al; }
            }
        }

        // ---- P = exp(s - m)  (f32 row-sum partials; f16 to LDS for MFMA) ----
        #pragma unroll
        for (int r = 0; r < 4; ++r) {
            const int prow = wq * 16 + quad * 4 + r;
            #pragma unroll
            for (int nt = 0; nt < 4; ++nt) {
                float p = __expf(sv[nt][r] - mreg[r]);
                Lp[r] += p;
                const int col = nt * 16 + m;
                Pb[swz8(prow, col >> 3) + (col & 7)] = f2h(p);
            }
        }

        const int qrow = wq * 16 + m;
        h8 pa0 = *(const h8*)&Pb[swz8(qrow, quad)];
        h8 pa1 = *(const h8*)&Pb[swz8(qrow, quad + 4)];

        // ---- PV ----
        #pragma unroll
        for (int dt = 0; dt < 4; ++dt) {
            const int vr_ = dt * 16 + m;
            h8 b0 = *(const h8*)&Vr[cur][swz8(vr_, quad)];
            h8 b1 = *(const h8*)&Vr[cur][swz8(vr_, quad + 4)];
            h8 d0 = *(const h8*)&Vi[cur][swz8(vr_, quad)];
            h8 d1 = *(const h8*)&Vi[cur][swz8(vr_, quad + 4)];
            __builtin_amdgcn_s_setprio(1);
            Ovr[dt] = MFMA_F16(pa0, b0, Ovr[dt], 0, 0, 0);
            Ovr[dt] = MFMA_F16(pa1, b1, Ovr[dt], 0, 0, 0);
            Ovi[dt] = MFMA_F16(pa0, d0, Ovi[dt], 0, 0, 0);
            Ovi[dt] = MFMA_F16(pa1, d1, Ovi[dt], 0, 0, 0);
            __builtin_amdgcn_s_setprio(0);
        }

        __syncthreads();    // buf cur consumed; buf cur^1 fully written
    }

    // =======================================================================
    // Fused epilogue: L-normalize -> joint RMS -> gate -> out-projection.
    // =======================================================================
    {
        // finish L across the 16 m-lanes; normalize O in f32
        #pragma unroll
        for (int r = 0; r < 4; ++r) {
            float x = Lp[r];
            x += __shfl_xor(x, 1);
            x += __shfl_xor(x, 2);
            x += __shfl_xor(x, 4);
            x += __shfl_xor(x, 8);
            float inv = 1.f / x;
            #pragma unroll
            for (int dt = 0; dt < 4; ++dt) { Ovr[dt][r] *= inv; Ovi[dt][r] *= inv; }
        }

        // per-row sum of squares over this wave's 64 cols (one branch, r+i)
        float ssp[4];
        #pragma unroll
        for (int r = 0; r < 4; ++r) {
            float s = 0.f;
            #pragma unroll
            for (int dt = 0; dt < 4; ++dt)
                s += Ovr[dt][r] * Ovr[dt][r] + Ovi[dt][r] * Ovi[dt][r];
            s += __shfl_xor(s, 1);
            s += __shfl_xor(s, 2);
            s += __shfl_xor(s, 4);
            s += __shfl_xor(s, 8);
            ssp[r] = s;
        }
        if (m == 0) {
            #pragma unroll
            for (int r = 0; r < 4; ++r)
                ssL[br][wr * 16 + quad * 4 + r] = ssp[r];
        }
        __syncthreads();

        // rms^-1 per row (joint over both branches = all 128 interleaved cols)
        float rmi[4];
        #pragma unroll
        for (int r = 0; r < 4; ++r) {
            const int row = wr * 16 + quad * 4 + r;
            float ss = ssL[0][row] + ssL[1][row];
            rmi[r] = 1.f / sqrtf(ss * (1.f / 128.f) + 1e-5f);
        }

        // X = gate(gr,gi) * (norm * subw): cols c = 2*(dt*16+m)+br, dt<2.
        // Written f16 to freed Pb: Xr = Pb[0..4095], Xi = Pb[4096..8191].
        u16* Xr = Pb;
        u16* Xi = Pb + 4096;
        const int growb = h * 2048 + qt * 64;
        #pragma unroll
        for (int dt = 0; dt < 2; ++dt) {
            const int k = dt * 16 + m;
            const int c = 2 * k + br;
            const float sw = subw[c];
            #pragma unroll
            for (int r = 0; r < 4; ++r) {
                const int row = wr * 16 + quad * 4 + r;
                const size_t gidx = (size_t)(growb + row) * 64 + c;
                float g_r = out_gr[gidx];
                float g_i = out_gi[gidx];
                float a_r = Ovr[dt][r] * rmi[r] * sw;
                float a_i = Ovi[dt][r] * rmi[r] * sw;
                const int off = swz8(row, c >> 3) + (c & 7);
                Xr[off] = f2h(g_r * a_r - g_i * a_i);
                Xi[off] = f2h(g_r * a_i + g_i * a_r);
            }
        }
        __syncthreads();

        // out-projection: wave (ct = wq&3, rh2 = wq>>2); 2 row-tiles each.
        const int ct  = wq & 3;
        const int rh2 = wq >> 2;
        const int c   = ct * 16 + m;
        const float br_ = obr[c], bi_ = obi[c];
        const u16* pR = pk + (40 + ct) * 1024;
        const u16* pI = pk + (44 + ct) * 1024;
        h8 Br0 = *(const h8*)(pR + l * 8);
        h8 Br1 = *(const h8*)(pR + 512 + l * 8);
        h8 Bi0 = *(const h8*)(pI + l * 8);
        h8 Bi1 = *(const h8*)(pI + 512 + l * 8);

        #pragma unroll
        for (int rt = 0; rt < 2; ++rt) {
            const int arow = rh2 * 32 + rt * 16 + m;
            h8 Ar0 = *(const h8*)&Xr[swz8(arow, quad)];
            h8 Ar1 = *(const h8*)&Xr[swz8(arow, quad + 4)];
            h8 Ai0 = *(const h8*)&Xi[swz8(arow, quad)];
            h8 Ai1 = *(const h8*)&Xi[swz8(arow, quad + 4)];
            h8 nAi0 = neg_h8(Ai0), nAi1 = neg_h8(Ai1);

            f4 Cr = (f4)0.f, Ci = (f4)0.f;
            Cr = MFMA_F16(Ar0,  Br0, Cr, 0, 0, 0);
            Cr = MFMA_F16(Ar1,  Br1, Cr, 0, 0, 0);
            Cr = MFMA_F16(nAi0, Bi0, Cr, 0, 0, 0);
            Cr = MFMA_F16(nAi1, Bi1, Cr, 0, 0, 0);
            Ci = MFMA_F16(Ar0,  Bi0, Ci, 0, 0, 0);
            Ci = MFMA_F16(Ar1,  Bi1, Ci, 0, 0, 0);
            Ci = MFMA_F16(Ai0,  Br0, Ci, 0, 0, 0);
            Ci = MFMA_F16(Ai1,  Br1, Ci, 0, 0, 0);

            #pragma unroll
            for (int r = 0; r < 4; ++r) {
                const int row = rh2 * 32 + rt * 16 + quad * 4 + r;
                const size_t g = (size_t)(growb + row) * 64 + c;
                out_r[g] = Cr[r] + br_;
                out_i[g] = Ci[r] + bi_;
            }
        }
    }
}

// ---------------------------------------------------------------------------
extern "C" void kernel_launch(void* const* d_in, const int* in_sizes, int n_in,
                              void* d_out, int out_size, void* d_ws, size_t ws_size,
                              hipStream_t stream)
{
    (void)in_sizes; (void)n_in; (void)out_size; (void)ws_size;

    float* out    = (float*)d_out;
    float* out_r  = out;
    float* out_i  = out + (size_t)NTOT;
    float* out_gr = out + 2 * (size_t)NTOT;
    float* out_gi = out + 3 * (size_t)NTOT;

    char* w = (char*)d_ws;
    const size_t N = (size_t)NTOT;
    u16* q1r = (u16*)w; w += N * 2;
    u16* q1i = (u16*)w; w += N * 2;
    u16* q2r = (u16*)w; w += N * 2;
    u16* q2i = (u16*)w; w += N * 2;
    u16* kpr = (u16*)w; w += N * 2;
    u16* kpi = (u16*)w; w += N * 2;
    u16* vtr = (u16*)w; w += N * 2;   // [h][d][s]
    u16* vti = (u16*)w; w += N * 2;   // [h][d][s]
    u16* pk  = (u16*)w;               // 96KB packed weights

    prep_kernel<<<dim3(48), dim3(128), 0, stream>>>(
        (const float*)d_in[10], (const float*)d_in[11],
        (const float*)d_in[14], (const float*)d_in[15],
        (const float*)d_in[18], (const float*)d_in[19],
        (const float*)d_in[22], (const float*)d_in[23],
        (const float*)d_in[26], (const float*)d_in[27],
        pk);

    proj_kernel<<<dim3(1024), dim3(256), 0, stream>>>(
        (const float*)d_in[0], (const float*)d_in[1],
        (const float*)d_in[2], (const float*)d_in[3],
        (const float*)d_in[4], (const float*)d_in[5],
        (const float*)d_in[6], (const float*)d_in[7],
        (const float*)d_in[8], (const float*)d_in[9],
        pk,
        (const float*)d_in[12], (const float*)d_in[13],
        (const float*)d_in[16], (const float*)d_in[17],
        (const float*)d_in[20], (const float*)d_in[21],
        (const float*)d_in[24], (const float*)d_in[25],
        q1r, q1i, q2r, q2i, kpr, kpi, vtr, vti, out_gr, out_gi);

    attn_kernel<<<dim3(SQ / 64, 1, NH), dim3(512), 0, stream>>>(
        q1r, q1i, q2r, q2i, kpr, kpi, vtr, vti,
        pk, (const float*)d_in[34],
        (const float*)d_in[28], (const float*)d_in[29],
        out_gr, out_gi, out_r, out_i);
}

// Round 11
// 224.481 us; speedup vs baseline: 1.2643x; 1.0244x over previous
//
#include <hip/hip_runtime.h>
#include <hip/hip_bf16.h>

#define NH 8
#define SQ 2048
#define HD 64
#define NTOT (NH * SQ * HD)   // 1048576

typedef unsigned short u16;
typedef unsigned int u32;
typedef __attribute__((ext_vector_type(8))) unsigned short us8;
typedef __attribute__((ext_vector_type(4))) unsigned short us4v;
typedef __attribute__((ext_vector_type(8))) _Float16 h8;   // MFMA f16 A/B fragment
typedef __attribute__((ext_vector_type(4))) float f4;      // MFMA C/D fragment
typedef __attribute__((ext_vector_type(4))) u32 u4;

#define MFMA_F16 __builtin_amdgcn_mfma_f32_16x16x32_f16

__device__ __forceinline__ u16 f2h(float f) {
    union { _Float16 h; u16 u; } c; c.h = (_Float16)f; return c.u;
}
__device__ __forceinline__ float h2f(u16 u) {
    union { _Float16 h; u16 u; } c; c.u = u; return (float)c.h;
}
__device__ __forceinline__ h8 neg_h8(h8 a) {
    union { h8 h; u4 u; } c; c.h = a;
    c.u ^= 0x80008000u;
    return c.h;
}
// 8 contiguous f32 -> f16x8 fragment (two float4 loads, hw cvt)
__device__ __forceinline__ h8 pack8h(const float* p) {
    float4 a = ((const float4*)p)[0];
    float4 b = ((const float4*)p)[1];
    h8 r;
    r[0] = (_Float16)a.x; r[1] = (_Float16)a.y; r[2] = (_Float16)a.z; r[3] = (_Float16)a.w;
    r[4] = (_Float16)b.x; r[5] = (_Float16)b.y; r[6] = (_Float16)b.z; r[7] = (_Float16)b.w;
    return r;
}

// T2 swizzle: pitch 64 u16 (128B rows), 16B-chunk index XOR'd with row&7.
__device__ __forceinline__ int swz8(int row, int chunk) {   // u16 offset of 8-u16 chunk
    return row * 64 + ((chunk ^ (row & 7)) << 3);
}

struct Afrag { h8 r0, r1, i0, i1, ni0, ni1; };

// ---------------------------------------------------------------------------
// Prep kernel (unchanged): pack ALL weights into MFMA B-fragment planes.
// ---------------------------------------------------------------------------
__global__ __launch_bounds__(128) void prep_kernel(
    const float* __restrict__ qwr, const float* __restrict__ qwi,
    const float* __restrict__ kwr, const float* __restrict__ kwi,
    const float* __restrict__ vwr, const float* __restrict__ vwi,
    const float* __restrict__ gwr, const float* __restrict__ gwi,
    const float* __restrict__ owr, const float* __restrict__ owi,
    u16* __restrict__ pk)
{
    const int b = blockIdx.x;
    const float* W; int nt;
    if (b < 8)       { W = qwr; nt = b; }
    else if (b < 16) { W = qwi; nt = b - 8; }
    else if (b < 20) { W = kwr; nt = b - 16; }
    else if (b < 24) { W = kwi; nt = b - 20; }
    else if (b < 28) { W = vwr; nt = b - 24; }
    else if (b < 32) { W = vwi; nt = b - 28; }
    else if (b < 36) { W = gwr; nt = b - 32; }
    else if (b < 40) { W = gwi; nt = b - 36; }
    else if (b < 44) { W = owr; nt = b - 40; }
    else             { W = owi; nt = b - 44; }
    const int t = threadIdx.x, hf = t >> 6, l = t & 63;
    const int quad = l >> 4, m16 = l & 15;
    h8 v = pack8h(W + (nt * 16 + m16) * 64 + hf * 32 + quad * 8);
    *(h8*)(pk + b * 1024 + hf * 512 + l * 8) = v;
}

// ---------------------------------------------------------------------------
// Kernel 1: MFMA complex projections (unchanged from R10).
// ---------------------------------------------------------------------------
__global__ __launch_bounds__(256) void proj_kernel(
    const float* __restrict__ q_r, const float* __restrict__ q_i,
    const float* __restrict__ k_r, const float* __restrict__ k_i,
    const float* __restrict__ v_r, const float* __restrict__ v_i,
    const float* __restrict__ pe_q_r, const float* __restrict__ pe_q_i,
    const float* __restrict__ pe_k_r, const float* __restrict__ pe_k_i,
    const u16* __restrict__ pk,
    const float* __restrict__ qbr, const float* __restrict__ qbi,
    const float* __restrict__ kbr, const float* __restrict__ kbi,
    const float* __restrict__ vbr, const float* __restrict__ vbi,
    const float* __restrict__ gbr, const float* __restrict__ gbi,
    u16* __restrict__ q1r, u16* __restrict__ q1i,
    u16* __restrict__ q2r, u16* __restrict__ q2i,
    u16* __restrict__ kpr, u16* __restrict__ kpi,
    u16* __restrict__ vtr, u16* __restrict__ vti,
    float* __restrict__ out_gr, float* __restrict__ out_gi)
{
    __shared__ __align__(16) u16 Sqr[16 * 64], Sqi[16 * 64];
    __shared__ __align__(16) u16 Skr[16 * 64], Ski[16 * 64];
    __shared__ __align__(16) u16 Svr[16 * 64], Svi[16 * 64];
    __shared__ __align__(16) u16 Oq1r[16 * 68], Oq1i[16 * 68];
    __shared__ __align__(16) u16 Oq2r[16 * 68], Oq2i[16 * 68];
    __shared__ __align__(16) u16 Okr[16 * 68],  Oki[16 * 68];
    __shared__ __align__(16) float Ogr[16 * 68], Ogi[16 * 68];

    const int t = threadIdx.x;
    const int wv = t >> 6, l = t & 63;
    const int quad = l >> 4, m16 = l & 15;
    const int rowbase = blockIdx.x * 16;
    const int h = rowbase >> 11;
    const int l8 = l * 8;

    {
        const int r = t >> 4, c4 = (t & 15) * 4;
        const int off = swz8(r, c4 >> 3) + (c4 & 7);
        const size_t gi = (size_t)(rowbase + r) * 64 + c4;
        auto stage = [&](const float* src, u16* dst) {
            float4 v = *(const float4*)(src + gi);
            us4v p;
            p[0] = f2h(v.x); p[1] = f2h(v.y); p[2] = f2h(v.z); p[3] = f2h(v.w);
            *(us4v*)&dst[off] = p;
        };
        stage(q_r, Sqr); stage(q_i, Sqi);
        stage(k_r, Skr); stage(k_i, Ski);
        stage(v_r, Svr); stage(v_i, Svi);
    }
    __syncthreads();

    auto loadA = [&](const u16* Sr, const u16* Si) {
        Afrag a;
        a.r0 = *(const h8*)&Sr[swz8(m16, quad)];
        a.r1 = *(const h8*)&Sr[swz8(m16, quad + 4)];
        a.i0 = *(const h8*)&Si[swz8(m16, quad)];
        a.i1 = *(const h8*)&Si[swz8(m16, quad + 4)];
        a.ni0 = neg_h8(a.i0);
        a.ni1 = neg_h8(a.i1);
        return a;
    };

    auto ctile = [&](const Afrag& A, int planeR, int planeI, f4& Cr, f4& Ci) {
        const u16* pR = pk + planeR * 1024;
        const u16* pI = pk + planeI * 1024;
        h8 Br0 = *(const h8*)(pR + l8);
        h8 Br1 = *(const h8*)(pR + 512 + l8);
        h8 Bi0 = *(const h8*)(pI + l8);
        h8 Bi1 = *(const h8*)(pI + 512 + l8);
        Cr = (f4)0.f; Ci = (f4)0.f;
        Cr = MFMA_F16(A.r0,  Br0, Cr, 0, 0, 0);
        Cr = MFMA_F16(A.r1,  Br1, Cr, 0, 0, 0);
        Cr = MFMA_F16(A.ni0, Bi0, Cr, 0, 0, 0);
        Cr = MFMA_F16(A.ni1, Bi1, Cr, 0, 0, 0);
        Ci = MFMA_F16(A.r0,  Bi0, Ci, 0, 0, 0);
        Ci = MFMA_F16(A.r1,  Bi1, Ci, 0, 0, 0);
        Ci = MFMA_F16(A.i0,  Br0, Ci, 0, 0, 0);
        Ci = MFMA_F16(A.i1,  Br1, Ci, 0, 0, 0);
    };

    auto qtile = [&](const Afrag& A, int nt) {
        f4 Cr, Ci;
        ctile(A, nt, 8 + nt, Cr, Ci);
        int c = nt * 16 + m16;
        float br = qbr[c], bi = qbi[c];
        int dd = c >> 1, pc = c & 63;
        u16* dR = (c & 1) ? Oq2r : Oq1r;
        u16* dI = (c & 1) ? Oq2i : Oq1i;
        #pragma unroll
        for (int r = 0; r < 4; ++r) {
            int row = quad * 4 + r;
            int g = rowbase + row;
            dR[row * 68 + dd] = f2h(Cr[r] + br + pe_q_r[g * 64 + pc]);
            dI[row * 68 + dd] = f2h(Ci[r] + bi + pe_q_i[g * 64 + pc]);
        }
    };
    auto ktile = [&](const Afrag& A, int nt) {
        f4 Cr, Ci;
        ctile(A, 16 + nt, 20 + nt, Cr, Ci);
        int c = nt * 16 + m16;
        float br = kbr[c], bi = kbi[c];
        #pragma unroll
        for (int r = 0; r < 4; ++r) {
            int row = quad * 4 + r;
            int g = rowbase + row;
            Okr[row * 68 + c] = f2h(Cr[r] + br + pe_k_r[g * 64 + c]);
            Oki[row * 68 + c] = f2h(Ci[r] + bi + pe_k_i[g * 64 + c]);
        }
    };
    auto vtile = [&](const Afrag& A, int nt) {
        f4 Cr, Ci;
        ctile(A, 24 + nt, 28 + nt, Cr, Ci);
        int c = nt * 16 + m16;
        float br = vbr[c], bi = vbi[c];
        int s0 = (rowbase & 2047) + quad * 4;
        size_t tix = (size_t)(h * 64 + c) * 2048 + s0;
        us4v pr, pi;
        #pragma unroll
        for (int r = 0; r < 4; ++r) {
            pr[r] = f2h(Cr[r] + br);
            pi[r] = f2h(Ci[r] + bi);
        }
        *(us4v*)&vtr[tix] = pr;
        *(us4v*)&vti[tix] = pi;
    };
    auto gtile = [&](const Afrag& A, int nt) {
        f4 Cr, Ci;
        ctile(A, 32 + nt, 36 + nt, Cr, Ci);
        int c = nt * 16 + m16;
        float br = gbr[c], bi = gbi[c];
        #pragma unroll
        for (int r = 0; r < 4; ++r) {
            int row = quad * 4 + r;
            Ogr[row * 68 + c] = Cr[r] + br;
            Ogi[row * 68 + c] = Ci[r] + bi;
        }
    };

    if (wv == 0) {
        Afrag Aq = loadA(Sqr, Sqi);
        qtile(Aq, 0); qtile(Aq, 1); qtile(Aq, 2); qtile(Aq, 3); qtile(Aq, 4);
    } else if (wv == 1) {
        Afrag Aq = loadA(Sqr, Sqi);
        qtile(Aq, 5); qtile(Aq, 6); qtile(Aq, 7);
        gtile(Aq, 0); gtile(Aq, 1);
    } else if (wv == 2) {
        Afrag Ak = loadA(Skr, Ski);
        ktile(Ak, 0); ktile(Ak, 1); ktile(Ak, 2); ktile(Ak, 3);
        Afrag Aq = loadA(Sqr, Sqi);
        gtile(Aq, 2);
    } else {
        Afrag Av = loadA(Svr, Svi);
        vtile(Av, 0); vtile(Av, 1); vtile(Av, 2); vtile(Av, 3);
        Afrag Aq = loadA(Sqr, Sqi);
        gtile(Aq, 3);
    }
    __syncthreads();

    {
        const int r = t >> 4, c4 = (t & 15) * 4;
        const size_t gi = (size_t)(rowbase + r) * 64 + c4;
        const int lo = r * 68 + c4;
        *(us4v*)&q1r[gi] = *(const us4v*)&Oq1r[lo];
        *(us4v*)&q1i[gi] = *(const us4v*)&Oq1i[lo];
        *(us4v*)&q2r[gi] = *(const us4v*)&Oq2r[lo];
        *(us4v*)&q2i[gi] = *(const us4v*)&Oq2i[lo];
        *(us4v*)&kpr[gi] = *(const us4v*)&Okr[lo];
        *(us4v*)&kpi[gi] = *(const us4v*)&Oki[lo];
        *(float4*)&out_gr[gi] = *(const float4*)&Ogr[lo];
        *(float4*)&out_gi[gi] = *(const float4*)&Ogi[lo];
    }
}

// ---------------------------------------------------------------------------
// Kernel 2: MFMA flash attention + fused epilogue.
//   Round-19: SWAPPED QK^T (A=K, B=Q) -> lane holds S[kk=nt*16+quad*4+r]
//   [q=m]: 16 consecutive k-scores for ONE q-row per lane.
//   - row-max: 15 in-lane fmax + 2 shfl (was 16 shfl)
//   - P write: 4x ds_write_b64 packed (was 16 scalar b16)
//   - m/L state scalar per lane (q=m); rescale factor + final 1/L moved to
//     O's q=quad*4+r rows via 4 __shfl (rescale rare by defer-max; final 1x)
//   PV path, Pb read layout, and the whole fused epilogue are UNCHANGED.
// ---------------------------------------------------------------------------
__global__ __launch_bounds__(512, 1) void attn_kernel(
    const u16* __restrict__ q1r, const u16* __restrict__ q1i,
    const u16* __restrict__ q2r, const u16* __restrict__ q2i,
    const u16* __restrict__ kpr, const u16* __restrict__ kpi,
    const u16* __restrict__ vtr, const u16* __restrict__ vti,
    const u16* __restrict__ pk,
    const float* __restrict__ subw,
    const float* __restrict__ obr, const float* __restrict__ obi,
    const float* __restrict__ out_gr, const float* __restrict__ out_gi,
    float* __restrict__ out_r, float* __restrict__ out_i)
{
    __shared__ __align__(16) u16 Kr[2][64 * 64], Ki[2][64 * 64];
    __shared__ __align__(16) u16 Vr[2][64 * 64], Vi[2][64 * 64];
    __shared__ __align__(16) u16 Pb[128 * 64];
    __shared__ float ssL[2][64];

    const int t  = threadIdx.x;      // 0..511
    const int qt = blockIdx.x;
    const int h  = blockIdx.z;

    const int wq   = t >> 6;         // wave 0..7
    const int br   = wq >> 2;        // branch
    const int wr   = wq & 3;         // 16-row block within the 64-row q tile
    const int l    = t & 63;
    const int quad = l >> 4;
    const int m    = l & 15;

    const u16* Qsr = br ? q2r : q1r;
    const u16* Qsi = br ? q2i : q1i;
    const int hbase = h * SQ * 64;
    const int qbase = hbase + qt * 64 * 64;
    const int vbase = h * 64 * SQ;

    const u16* qrr = Qsr + qbase + (wr * 16 + m) * 64;
    const u16* qri = Qsi + qbase + (wr * 16 + m) * 64;
    h8 Qr0 = *(const h8*)(qrr + quad * 8);
    h8 Qr1 = *(const h8*)(qrr + 32 + quad * 8);
    h8 Qi0 = *(const h8*)(qri + quad * 8);
    h8 Qi1 = *(const h8*)(qri + 32 + quad * 8);

    // ---- staging: 512 threads cover one 64x64 u16 tile per array ----
    const int sr0 = t >> 3;           // row 0..63
    const int sc  = t & 7;            // 8-u16 chunk
    us8 rK, rC, rV, rW;

    auto issue = [&](int kt) {
        const int kb = hbase + kt * 4096;
        const int vb = vbase + kt * 64;
        const int sc8 = sc * 8;
        rK = *(const us8*)(kpr + kb + sr0 * 64 + sc8);
        rC = *(const us8*)(kpi + kb + sr0 * 64 + sc8);
        rV = *(const us8*)(vtr + vb + sr0 * SQ + sc8);
        rW = *(const us8*)(vti + vb + sr0 * SQ + sc8);
    };
    auto commit = [&](int b) {
        const int o = swz8(sr0, sc);
        *(us8*)&Kr[b][o] = rK;
        *(us8*)&Ki[b][o] = rC;
        *(us8*)&Vr[b][o] = rV;
        *(us8*)&Vi[b][o] = rW;
    };

    // softmax state per lane, at q = wq*16 + m (replicated across the 4 quads)
    float mreg = -1e30f, Lp = 0.f;
    f4 Ovr[4], Ovi[4];
    #pragma unroll
    for (int d = 0; d < 4; ++d) { Ovr[d] = (f4)0.f; Ovi[d] = (f4)0.f; }

    // prologue: tile0 -> buf0; loads for tile1 in flight
    issue(0);
    commit(0);          // compiler inserts vmcnt wait
    issue(1);
    __syncthreads();

    const int prow = wq * 16 + m;     // this lane's q-row slot in Pb

    for (int kt = 0; kt < 32; ++kt) {
        const int cur = kt & 1;
        if (kt < 31) commit(cur ^ 1);    // tile kt+1 regs -> other buffer
        if (kt < 30) issue(kt + 2);      // loads in flight across this iter

        // ---- swapped QK^T: D[kk=nt*16+quad*4+r][q=m] ----
        float sv[4][4];
        #pragma unroll
        for (int nt = 0; nt < 4; ++nt) {
            const int kr = nt * 16 + m;
            h8 k0 = *(const h8*)&Kr[cur][swz8(kr, quad)];
            h8 k1 = *(const h8*)&Kr[cur][swz8(kr, quad + 4)];
            h8 c0 = *(const h8*)&Ki[cur][swz8(kr, quad)];
            h8 c1 = *(const h8*)&Ki[cur][swz8(kr, quad + 4)];
            h8 nc0 = neg_h8(c0);
            h8 nc1 = neg_h8(c1);
            f4 ar = (f4)0.f, ai = (f4)0.f;
            __builtin_amdgcn_s_setprio(1);
            ar = MFMA_F16(k0,  Qr0, ar, 0, 0, 0);
            ar = MFMA_F16(k1,  Qr1, ar, 0, 0, 0);
            ar = MFMA_F16(c0,  Qi0, ar, 0, 0, 0);
            ar = MFMA_F16(c1,  Qi1, ar, 0, 0, 0);
            ai = MFMA_F16(k0,  Qi0, ai, 0, 0, 0);
            ai = MFMA_F16(k1,  Qi1, ai, 0, 0, 0);
            ai = MFMA_F16(nc0, Qr0, ai, 0, 0, 0);
            ai = MFMA_F16(nc1, Qr1, ai, 0, 0, 0);
            __builtin_amdgcn_s_setprio(0);
            #pragma unroll
            for (int r = 0; r < 4; ++r)
                sv[nt][r] = __builtin_amdgcn_sqrtf(ar[r] * ar[r] + ai[r] * ai[r] + 1e-8f) * 0.125f;
        }

        // ---- row max for q=m: in-lane tree over 16 + 2 cross-quad shfl ----
        float a0 = fmaxf(fmaxf(sv[0][0], sv[0][1]), fmaxf(sv[0][2], sv[0][3]));
        float a1 = fmaxf(fmaxf(sv[1][0], sv[1][1]), fmaxf(sv[1][2], sv[1][3]));
        float a2 = fmaxf(fmaxf(sv[2][0], sv[2][1]), fmaxf(sv[2][2], sv[2][3]));
        float a3 = fmaxf(fmaxf(sv[3][0], sv[3][1]), fmaxf(sv[3][2], sv[3][3]));
        float rv = fmaxf(fmaxf(a0, a1), fmaxf(a2, a3));
        rv = fmaxf(rv, __shfl_xor(rv, 16));
        rv = fmaxf(rv, __shfl_xor(rv, 32));

        // ---- T13 defer-max ----
        if (__any(rv > mreg + 8.f)) {
            float mn = fmaxf(mreg, rv);
            float al = __expf(mreg - mn);
            mreg = mn;
            Lp *= al;
            // O rows are q = quad*4 + r: fetch each row's factor
            #pragma unroll
            for (int r = 0; r < 4; ++r) {
                float alr = __shfl(al, quad * 4 + r);
                #pragma unroll
                for (int dt = 0; dt < 4; ++dt) { Ovr[dt][r] *= alr; Ovi[dt][r] *= alr; }
            }
        }

        // ---- P = exp(s - m): 4x packed b64 writes (wave-private stripe) ----
        #pragma unroll
        for (int nt = 0; nt < 4; ++nt) {
            us4v pw;
            #pragma unroll
            for (int r = 0; r < 4; ++r) {
                float p = __expf(sv[nt][r] - mreg);
                Lp += p;
                pw[r] = f2h(p);
            }
            // col block = nt*16 + quad*4: chunk = 2nt + (quad>>1), sub = (quad&1)*4
            *(us4v*)&Pb[swz8(prow, 2 * nt + (quad >> 1)) + ((quad & 1) << 2)] = pw;
        }

        h8 pa0 = *(const h8*)&Pb[swz8(prow, quad)];
        h8 pa1 = *(const h8*)&Pb[swz8(prow, quad + 4)];

        // ---- PV (unchanged) ----
        #pragma unroll
        for (int dt = 0; dt < 4; ++dt) {
            const int vr_ = dt * 16 + m;
            h8 b0 = *(const h8*)&Vr[cur][swz8(vr_, quad)];
            h8 b1 = *(const h8*)&Vr[cur][swz8(vr_, quad + 4)];
            h8 d0 = *(const h8*)&Vi[cur][swz8(vr_, quad)];
            h8 d1 = *(const h8*)&Vi[cur][swz8(vr_, quad + 4)];
            __builtin_amdgcn_s_setprio(1);
            Ovr[dt] = MFMA_F16(pa0, b0, Ovr[dt], 0, 0, 0);
            Ovr[dt] = MFMA_F16(pa1, b1, Ovr[dt], 0, 0, 0);
            Ovi[dt] = MFMA_F16(pa0, d0, Ovi[dt], 0, 0, 0);
            Ovi[dt] = MFMA_F16(pa1, d1, Ovi[dt], 0, 0, 0);
            __builtin_amdgcn_s_setprio(0);
        }

        __syncthreads();    // buf cur consumed; buf cur^1 fully written
    }

    // =======================================================================
    // Fused epilogue: L-normalize -> joint RMS -> gate -> out-projection.
    // =======================================================================
    {
        // finish L for q=m (sum over the 4 quad lanes), then redistribute
        // 1/L to this lane's O rows q = quad*4 + r.
        float x = Lp;
        x += __shfl_xor(x, 16);
        x += __shfl_xor(x, 32);
        float invq = 1.f / x;
        #pragma unroll
        for (int r = 0; r < 4; ++r) {
            float inv = __shfl(invq, quad * 4 + r);
            #pragma unroll
            for (int dt = 0; dt < 4; ++dt) { Ovr[dt][r] *= inv; Ovi[dt][r] *= inv; }
        }

        // per-row sum of squares over this wave's 64 cols (one branch, r+i)
        float ssp[4];
        #pragma unroll
        for (int r = 0; r < 4; ++r) {
            float s = 0.f;
            #pragma unroll
            for (int dt = 0; dt < 4; ++dt)
                s += Ovr[dt][r] * Ovr[dt][r] + Ovi[dt][r] * Ovi[dt][r];
            s += __shfl_xor(s, 1);
            s += __shfl_xor(s, 2);
            s += __shfl_xor(s, 4);
            s += __shfl_xor(s, 8);
            ssp[r] = s;
        }
        if (m == 0) {
            #pragma unroll
            for (int r = 0; r < 4; ++r)
                ssL[br][wr * 16 + quad * 4 + r] = ssp[r];
        }
        __syncthreads();

        // rms^-1 per row (joint over both branches = all 128 interleaved cols)
        float rmi[4];
        #pragma unroll
        for (int r = 0; r < 4; ++r) {
            const int row = wr * 16 + quad * 4 + r;
            float ss = ssL[0][row] + ssL[1][row];
            rmi[r] = 1.f / sqrtf(ss * (1.f / 128.f) + 1e-5f);
        }

        // X = gate(gr,gi) * (norm * subw): cols c = 2*(dt*16+m)+br, dt<2.
        u16* Xr = Pb;
        u16* Xi = Pb + 4096;
        const int growb = h * 2048 + qt * 64;
        #pragma unroll
        for (int dt = 0; dt < 2; ++dt) {
            const int k = dt * 16 + m;
            const int c = 2 * k + br;
            const float sw = subw[c];
            #pragma unroll
            for (int r = 0; r < 4; ++r) {
                const int row = wr * 16 + quad * 4 + r;
                const size_t gidx = (size_t)(growb + row) * 64 + c;
                float g_r = out_gr[gidx];
                float g_i = out_gi[gidx];
                float a_r = Ovr[dt][r] * rmi[r] * sw;
                float a_i = Ovi[dt][r] * rmi[r] * sw;
                const int off = swz8(row, c >> 3) + (c & 7);
                Xr[off] = f2h(g_r * a_r - g_i * a_i);
                Xi[off] = f2h(g_r * a_i + g_i * a_r);
            }
        }
        __syncthreads();

        // out-projection: wave (ct = wq&3, rh2 = wq>>2); 2 row-tiles each.
        const int ct  = wq & 3;
        const int rh2 = wq >> 2;
        const int c   = ct * 16 + m;
        const float br_ = obr[c], bi_ = obi[c];
        const u16* pR = pk + (40 + ct) * 1024;
        const u16* pI = pk + (44 + ct) * 1024;
        h8 Br0 = *(const h8*)(pR + l * 8);
        h8 Br1 = *(const h8*)(pR + 512 + l * 8);
        h8 Bi0 = *(const h8*)(pI + l * 8);
        h8 Bi1 = *(const h8*)(pI + 512 + l * 8);

        #pragma unroll
        for (int rt = 0; rt < 2; ++rt) {
            const int arow = rh2 * 32 + rt * 16 + m;
            h8 Ar0 = *(const h8*)&Xr[swz8(arow, quad)];
            h8 Ar1 = *(const h8*)&Xr[swz8(arow, quad + 4)];
            h8 Ai0 = *(const h8*)&Xi[swz8(arow, quad)];
            h8 Ai1 = *(const h8*)&Xi[swz8(arow, quad + 4)];
            h8 nAi0 = neg_h8(Ai0), nAi1 = neg_h8(Ai1);

            f4 Cr = (f4)0.f, Ci = (f4)0.f;
            Cr = MFMA_F16(Ar0,  Br0, Cr, 0, 0, 0);
            Cr = MFMA_F16(Ar1,  Br1, Cr, 0, 0, 0);
            Cr = MFMA_F16(nAi0, Bi0, Cr, 0, 0, 0);
            Cr = MFMA_F16(nAi1, Bi1, Cr, 0, 0, 0);
            Ci = MFMA_F16(Ar0,  Bi0, Ci, 0, 0, 0);
            Ci = MFMA_F16(Ar1,  Bi1, Ci, 0, 0, 0);
            Ci = MFMA_F16(Ai0,  Br0, Ci, 0, 0, 0);
            Ci = MFMA_F16(Ai1,  Br1, Ci, 0, 0, 0);

            #pragma unroll
            for (int r = 0; r < 4; ++r) {
                const int row = rh2 * 32 + rt * 16 + quad * 4 + r;
                const size_t g = (size_t)(growb + row) * 64 + c;
                out_r[g] = Cr[r] + br_;
                out_i[g] = Ci[r] + bi_;
            }
        }
    }
}

// ---------------------------------------------------------------------------
extern "C" void kernel_launch(void* const* d_in, const int* in_sizes, int n_in,
                              void* d_out, int out_size, void* d_ws, size_t ws_size,
                              hipStream_t stream)
{
    (void)in_sizes; (void)n_in; (void)out_size; (void)ws_size;

    float* out    = (float*)d_out;
    float* out_r  = out;
    float* out_i  = out + (size_t)NTOT;
    float* out_gr = out + 2 * (size_t)NTOT;
    float* out_gi = out + 3 * (size_t)NTOT;

    char* w = (char*)d_ws;
    const size_t N = (size_t)NTOT;
    u16* q1r = (u16*)w; w += N * 2;
    u16* q1i = (u16*)w; w += N * 2;
    u16* q2r = (u16*)w; w += N * 2;
    u16* q2i = (u16*)w; w += N * 2;
    u16* kpr = (u16*)w; w += N * 2;
    u16* kpi = (u16*)w; w += N * 2;
    u16* vtr = (u16*)w; w += N * 2;   // [h][d][s]
    u16* vti = (u16*)w; w += N * 2;   // [h][d][s]
    u16* pk  = (u16*)w;               // 96KB packed weights

    prep_kernel<<<dim3(48), dim3(128), 0, stream>>>(
        (const float*)d_in[10], (const float*)d_in[11],
        (const float*)d_in[14], (const float*)d_in[15],
        (const float*)d_in[18], (const float*)d_in[19],
        (const float*)d_in[22], (const float*)d_in[23],
        (const float*)d_in[26], (const float*)d_in[27],
        pk);

    proj_kernel<<<dim3(1024), dim3(256), 0, stream>>>(
        (const float*)d_in[0], (const float*)d_in[1],
        (const float*)d_in[2], (const float*)d_in[3],
        (const float*)d_in[4], (const float*)d_in[5],
        (const float*)d_in[6], (const float*)d_in[7],
        (const float*)d_in[8], (const float*)d_in[9],
        pk,
        (const float*)d_in[12], (const float*)d_in[13],
        (const float*)d_in[16], (const float*)d_in[17],
        (const float*)d_in[20], (const float*)d_in[21],
        (const float*)d_in[24], (const float*)d_in[25],
        q1r, q1i, q2r, q2i, kpr, kpi, vtr, vti, out_gr, out_gi);

    attn_kernel<<<dim3(SQ / 64, 1, NH), dim3(512), 0, stream>>>(
        q1r, q1i, q2r, q2i, kpr, kpi, vtr, vti,
        pk, (const float*)d_in[34],
        (const float*)d_in[28], (const float*)d_in[29],
        out_gr, out_gi, out_r, out_i);
}